// Round 14
// baseline (759.215 us; speedup 1.0000x reference)
//
#include <hip/hip_runtime.h>
#include <hip/hip_bf16.h>
#include <math.h>

#define D 512
#define NH 8
#define DHEAD 64
#define LAYERS 6
#define DFF 2048
#define BATCH 8
#define SEQ 128
#define ROWS (BATCH * SEQ)   // 1024

typedef float f32x4 __attribute__((ext_vector_type(4)));
typedef short bf16x8 __attribute__((ext_vector_type(8)));

__device__ __forceinline__ unsigned short f2b(float x) {
    return __builtin_bit_cast(unsigned short, __float2bfloat16(x));
}

// ---------------- embedding + positional encoding (both streams, z=2) -------
__global__ __launch_bounds__(256) void embed_pe_kernel(
        const int* __restrict__ tok0, const int* __restrict__ tok1,
        const float* __restrict__ emb0, const float* __restrict__ emb1,
        float* __restrict__ out0, float* __restrict__ out1)
{
    const int z = blockIdx.z;
    const int* tok = z ? tok1 : tok0;
    const float* emb = z ? emb1 : emb0;
    float* out = z ? out1 : out0;
    int i = blockIdx.x * 256 + threadIdx.x;
    int bs = i >> 9;
    int d  = i & 511;
    int s  = bs & (SEQ - 1);
    int tk = tok[bs];
    float dv  = expf(-(float)(d & ~1) * (9.210340371976184f / 512.0f));
    float arg = (float)s * dv;
    float pe  = (d & 1) ? cosf(arg) : sinf(arg);
    out[i] = emb[(size_t)tk * D + d] * 22.627416997969522f + pe;
}

// ---------------- batched multi-source transpose + fp32->bf16 ---------------
struct TSeg { const float* src; unsigned short* dst; int cnt; };
struct TMulti { TSeg seg[6]; };

__global__ __launch_bounds__(256) void transpose_multi_kernel(TMulti m, int R, int C)
{
    __shared__ float t[32][33];
    int z = blockIdx.z, s = 0;
    while (z >= m.seg[s].cnt) { z -= m.seg[s].cnt; ++s; }
    const float* src = m.seg[s].src + (size_t)z * R * C;
    unsigned short* dst = m.seg[s].dst + (size_t)z * R * C;
    const int r0 = blockIdx.y << 5, c0 = blockIdx.x << 5;
    const int tid = threadIdx.x;
    const int rr = tid >> 3, cc = (tid & 7) << 2;
    float4 v = *(const float4*)(src + (size_t)(r0 + rr) * C + c0 + cc);
    t[rr][cc] = v.x; t[rr][cc + 1] = v.y; t[rr][cc + 2] = v.z; t[rr][cc + 3] = v.w;
    __syncthreads();
    const int oc = tid >> 3, or4 = (tid & 7) << 2;
    ushort4 o;
    o.x = f2b(t[or4 + 0][oc]);
    o.y = f2b(t[or4 + 1][oc]);
    o.z = f2b(t[or4 + 2][oc]);
    o.w = f2b(t[or4 + 3][oc]);
    *(ushort4*)(dst + (size_t)(c0 + oc) * R + r0 + or4) = o;
}

// ---------------- LayerNorm: one wave per row of 512 ------------------------
template<int OUT_BF16>
__global__ __launch_bounds__(256) void ln_kernel(const float* __restrict__ x,
        const float* __restrict__ g, const float* __restrict__ bta,
        void* __restrict__ outp)
{
    int lane = threadIdx.x & 63;
    int row  = (blockIdx.x << 2) + (threadIdx.x >> 6);
    const float* xr = x + (size_t)row * D;
    int c = lane * 8;
    float4 v0 = *(const float4*)(xr + c);
    float4 v1 = *(const float4*)(xr + c + 4);
    float s  = v0.x + v0.y + v0.z + v0.w + v1.x + v1.y + v1.z + v1.w;
    float sq = v0.x*v0.x + v0.y*v0.y + v0.z*v0.z + v0.w*v0.w
             + v1.x*v1.x + v1.y*v1.y + v1.z*v1.z + v1.w*v1.w;
    #pragma unroll
    for (int o = 32; o; o >>= 1) {
        s  += __shfl_xor(s, o);
        sq += __shfl_xor(sq, o);
    }
    float mean = s * (1.0f / D);
    float var  = sq * (1.0f / D) - mean * mean;
    float inv  = rsqrtf(var + 1e-6f);
    float4 g0 = *(const float4*)(g + c),   g1 = *(const float4*)(g + c + 4);
    float4 b0 = *(const float4*)(bta + c), b1 = *(const float4*)(bta + c + 4);
    float4 o0, o1;
    o0.x = g0.x * (v0.x - mean) * inv + b0.x;
    o0.y = g0.y * (v0.y - mean) * inv + b0.y;
    o0.z = g0.z * (v0.z - mean) * inv + b0.z;
    o0.w = g0.w * (v0.w - mean) * inv + b0.w;
    o1.x = g1.x * (v1.x - mean) * inv + b1.x;
    o1.y = g1.y * (v1.y - mean) * inv + b1.y;
    o1.z = g1.z * (v1.z - mean) * inv + b1.z;
    o1.w = g1.w * (v1.w - mean) * inv + b1.w;
    if (OUT_BF16) {
        unsigned short* orow = (unsigned short*)outp + (size_t)row * D + c;
        uint4 o;
        o.x = (unsigned int)f2b(o0.x) | ((unsigned int)f2b(o0.y) << 16);
        o.y = (unsigned int)f2b(o0.z) | ((unsigned int)f2b(o0.w) << 16);
        o.z = (unsigned int)f2b(o1.x) | ((unsigned int)f2b(o1.y) << 16);
        o.w = (unsigned int)f2b(o1.z) | ((unsigned int)f2b(o1.w) << 16);
        *(uint4*)orow = o;
    } else {
        float* orow = (float*)outp + (size_t)row * D + c;
        *(float4*)(orow)     = o0;
        *(float4*)(orow + 4) = o1;
    }
}

// ---------------- bf16 MFMA GEMM, BM=64 (CKV batched GEMM only) -------------
template<int RESID, int RELU, int OUT_BF16>
__global__ __launch_bounds__(256) void mgemm_kernel(
        const unsigned short* __restrict__ A,
        const unsigned short* __restrict__ Wt,
        const float* __restrict__ bias,
        const float* __restrict__ Rp,
        void* __restrict__ Cout,
        int N, int K,
        long aZ, long wZ, long bZ, long cZ)
{
    __shared__ unsigned short As[2][64][72];
    __shared__ unsigned short Bs[2][64][72];
    const long z = blockIdx.z;
    const unsigned short* Ab = A  + z * aZ;
    const unsigned short* Wb = Wt + z * wZ;
    const float* biasb = bias + z * bZ;
    const int tid  = threadIdx.x;
    const int lane = tid & 63, wid = tid >> 6;
    const int wm = wid >> 1, wn = wid & 1;
    const int bm = blockIdx.y << 6, bn = blockIdx.x << 6;
    const int srow = tid >> 2, sk = (tid & 3) << 4;
    const unsigned short* Ag = Ab + (size_t)(bm + srow) * K + sk;
    const unsigned short* Bg = Wb + (size_t)(bn + srow) * K + sk;
    const int fr = lane & 15;
    const int fk = (lane >> 4) << 3;
    f32x4 acc[2][2];
    #pragma unroll
    for (int i = 0; i < 2; ++i)
        #pragma unroll
        for (int j = 0; j < 2; ++j)
            acc[i][j] = (f32x4){0.f, 0.f, 0.f, 0.f};

    uint4 a0 = *(const uint4*)Ag, a1 = *(const uint4*)(Ag + 8);
    uint4 b0 = *(const uint4*)Bg, b1 = *(const uint4*)(Bg + 8);
    const int T = K >> 6;
    for (int t = 0; t < T; ++t) {
        const int p = t & 1;
        *(uint4*)&As[p][srow][sk]     = a0;
        *(uint4*)&As[p][srow][sk + 8] = a1;
        *(uint4*)&Bs[p][srow][sk]     = b0;
        *(uint4*)&Bs[p][srow][sk + 8] = b1;
        if (t + 1 < T) {
            Ag += 64; Bg += 64;
            a0 = *(const uint4*)Ag; a1 = *(const uint4*)(Ag + 8);
            b0 = *(const uint4*)Bg; b1 = *(const uint4*)(Bg + 8);
        }
        __syncthreads();
        #pragma unroll
        for (int s = 0; s < 2; ++s) {
            bf16x8 af0 = *(const bf16x8*)&As[p][wm * 32 + fr][s * 32 + fk];
            bf16x8 af1 = *(const bf16x8*)&As[p][wm * 32 + 16 + fr][s * 32 + fk];
            bf16x8 bf0 = *(const bf16x8*)&Bs[p][wn * 32 + fr][s * 32 + fk];
            bf16x8 bf1 = *(const bf16x8*)&Bs[p][wn * 32 + 16 + fr][s * 32 + fk];
            acc[0][0] = __builtin_amdgcn_mfma_f32_16x16x32_bf16(af0, bf0, acc[0][0], 0, 0, 0);
            acc[0][1] = __builtin_amdgcn_mfma_f32_16x16x32_bf16(af0, bf1, acc[0][1], 0, 0, 0);
            acc[1][0] = __builtin_amdgcn_mfma_f32_16x16x32_bf16(af1, bf0, acc[1][0], 0, 0, 0);
            acc[1][1] = __builtin_amdgcn_mfma_f32_16x16x32_bf16(af1, bf1, acc[1][1], 0, 0, 0);
        }
    }
    const int cr   = (lane >> 4) << 2;
    const int ccol = lane & 15;
    #pragma unroll
    for (int i = 0; i < 2; ++i)
        #pragma unroll
        for (int j = 0; j < 2; ++j) {
            int col = bn + wn * 32 + j * 16 + ccol;
            float bsv = biasb[col];
            #pragma unroll
            for (int r = 0; r < 4; ++r) {
                int row = bm + wm * 32 + i * 16 + cr + r;
                float v = acc[i][j][r] + bsv;
                if (RESID) v += Rp[(size_t)row * N + col];
                if (RELU)  v = fmaxf(v, 0.f);
                if (OUT_BF16) ((unsigned short*)Cout + z * cZ)[(size_t)row * N + col] = f2b(v);
                else          ((float*)Cout)[(size_t)row * N + col] = v;
            }
        }
}

// ---------------- bf16 MFMA GEMM, BM=32 (high-occupancy per-layer GEMMs) ----
// 32x64 tile, BK=64, 256 threads = 4 waves 2x2; each wave 1 row-frag x 2
// col-frags of 16x16x32 (4 MFMA/K-step). Same dbuf/one-barrier structure and
// fragment maps as mgemm_kernel. Grid: (N/64, 1024/32=32).
template<int RESID, int RELU, int OUT_BF16>
__global__ __launch_bounds__(256) void mgemm32_kernel(
        const unsigned short* __restrict__ A,   // bf16 [1024][K]
        const unsigned short* __restrict__ Wt,  // bf16 [N][K]
        const float* __restrict__ bias,         // fp32 [N]
        const float* __restrict__ Rp,           // fp32 [1024][N]
        void* __restrict__ Cout,                // bf16 or fp32 [1024][N]
        int N, int K)
{
    __shared__ unsigned short As[2][32][72];
    __shared__ unsigned short Bs[2][64][72];
    const int tid  = threadIdx.x;
    const int lane = tid & 63, wid = tid >> 6;
    const int wm = wid >> 1, wn = wid & 1;
    const int bm = blockIdx.y << 5, bn = blockIdx.x << 6;
    const int srA = tid >> 3, skA = (tid & 7) << 3;   // A: 32 rows x 64k, 8 sh/thr
    const int srB = tid >> 2, skB = (tid & 3) << 4;   // B: 64 rows x 64k, 16 sh/thr
    const unsigned short* Ag = A  + (size_t)(bm + srA) * K + skA;
    const unsigned short* Bg = Wt + (size_t)(bn + srB) * K + skB;
    const int fr = lane & 15;
    const int fk = (lane >> 4) << 3;
    f32x4 acc[2];
    acc[0] = (f32x4){0.f, 0.f, 0.f, 0.f};
    acc[1] = (f32x4){0.f, 0.f, 0.f, 0.f};

    uint4 a0 = *(const uint4*)Ag;
    uint4 b0 = *(const uint4*)Bg, b1 = *(const uint4*)(Bg + 8);
    const int T = K >> 6;
    for (int t = 0; t < T; ++t) {
        const int p = t & 1;
        *(uint4*)&As[p][srA][skA]     = a0;
        *(uint4*)&Bs[p][srB][skB]     = b0;
        *(uint4*)&Bs[p][srB][skB + 8] = b1;
        if (t + 1 < T) {
            Ag += 64; Bg += 64;
            a0 = *(const uint4*)Ag;
            b0 = *(const uint4*)Bg; b1 = *(const uint4*)(Bg + 8);
        }
        __syncthreads();
        #pragma unroll
        for (int s = 0; s < 2; ++s) {
            bf16x8 af  = *(const bf16x8*)&As[p][wm * 16 + fr][s * 32 + fk];
            bf16x8 bf0 = *(const bf16x8*)&Bs[p][wn * 32 + fr][s * 32 + fk];
            bf16x8 bf1 = *(const bf16x8*)&Bs[p][wn * 32 + 16 + fr][s * 32 + fk];
            acc[0] = __builtin_amdgcn_mfma_f32_16x16x32_bf16(af, bf0, acc[0], 0, 0, 0);
            acc[1] = __builtin_amdgcn_mfma_f32_16x16x32_bf16(af, bf1, acc[1], 0, 0, 0);
        }
    }
    const int cr   = (lane >> 4) << 2;
    const int ccol = lane & 15;
    #pragma unroll
    for (int j = 0; j < 2; ++j) {
        int col = bn + wn * 32 + j * 16 + ccol;
        float bsv = bias[col];
        #pragma unroll
        for (int r = 0; r < 4; ++r) {
            int row = bm + wm * 16 + cr + r;
            float v = acc[j][r] + bsv;
            if (RESID) v += Rp[(size_t)row * N + col];
            if (RELU)  v = fmaxf(v, 0.f);
            if (OUT_BF16) ((unsigned short*)Cout)[(size_t)row * N + col] = f2b(v);
            else          ((float*)Cout)[(size_t)row * N + col] = v;
        }
    }
}

// ============ shared attention phase =========================================
template<int CAUSAL>
__device__ __forceinline__ void attn_phase(
        const unsigned short* Ks, const unsigned short* Vt,
        const unsigned short* Qs, unsigned short* Ps,
        int qbase, int brow, int hoff, unsigned short* __restrict__ Op,
        int lane, int wid)
{
    const int fr = lane & 15, fg = lane >> 4;
    f32x4 accs[8];
    #pragma unroll
    for (int kf = 0; kf < 8; ++kf) accs[kf] = (f32x4){0.f, 0.f, 0.f, 0.f};
    bf16x8 aq0 = *(const bf16x8*)&Qs[(wid * 16 + fr) * 72 + fg * 8];
    bf16x8 aq1 = *(const bf16x8*)&Qs[(wid * 16 + fr) * 72 + 32 + fg * 8];
    #pragma unroll
    for (int kf = 0; kf < 8; ++kf) {
        bf16x8 bk0 = *(const bf16x8*)&Ks[(kf * 16 + fr) * 72 + fg * 8];
        bf16x8 bk1 = *(const bf16x8*)&Ks[(kf * 16 + fr) * 72 + 32 + fg * 8];
        accs[kf] = __builtin_amdgcn_mfma_f32_16x16x32_bf16(aq0, bk0, accs[kf], 0, 0, 0);
        accs[kf] = __builtin_amdgcn_mfma_f32_16x16x32_bf16(aq1, bk1, accs[kf], 0, 0, 0);
    }
    const float SC = 0.125f * 1.44269504f;
    float linv[4];
    #pragma unroll
    for (int r = 0; r < 4; ++r) {
        int qrow = qbase + wid * 16 + fg * 4 + r;
        float sv[8];
        #pragma unroll
        for (int kf = 0; kf < 8; ++kf) {
            float s = accs[kf][r] * SC;
            if (CAUSAL) {
                int key = kf * 16 + fr;
                if (key > qrow) s = -1e30f;
            }
            sv[kf] = s;
        }
        float m = sv[0];
        #pragma unroll
        for (int kf = 1; kf < 8; ++kf) m = fmaxf(m, sv[kf]);
        #pragma unroll
        for (int o = 1; o < 16; o <<= 1) m = fmaxf(m, __shfl_xor(m, o));
        float l = 0.f;
        #pragma unroll
        for (int kf = 0; kf < 8; ++kf) {
            float p = exp2f(sv[kf] - m);
            l += p;
            Ps[(wid * 16 + fg * 4 + r) * 136 + kf * 16 + fr] = f2b(p);
        }
        #pragma unroll
        for (int o = 1; o < 16; o <<= 1) l += __shfl_xor(l, o);
        linv[r] = 1.f / l;
    }
    f32x4 acco[4];
    #pragma unroll
    for (int df = 0; df < 4; ++df) acco[df] = (f32x4){0.f, 0.f, 0.f, 0.f};
    #pragma unroll
    for (int ks = 0; ks < 4; ++ks) {
        bf16x8 pa = *(const bf16x8*)&Ps[(wid * 16 + fr) * 136 + ks * 32 + fg * 8];
        #pragma unroll
        for (int df = 0; df < 4; ++df) {
            bf16x8 vb = *(const bf16x8*)&Vt[(df * 16 + fr) * 136 + ks * 32 + fg * 8];
            acco[df] = __builtin_amdgcn_mfma_f32_16x16x32_bf16(pa, vb, acco[df], 0, 0, 0);
        }
    }
    #pragma unroll
    for (int df = 0; df < 4; ++df)
        #pragma unroll
        for (int r = 0; r < 4; ++r) {
            int qrow = qbase + wid * 16 + fg * 4 + r;
            Op[(size_t)(brow + qrow) * D + hoff + df * 16 + fr] = f2b(acco[df][r] * linv[r]);
        }
}

// ---------------- standalone attention (proven) -----------------------------
template<int CAUSAL>
__global__ __launch_bounds__(256) void attn_kernel(
        const unsigned short* __restrict__ Qp, int qs,
        const unsigned short* __restrict__ Kp,
        const unsigned short* __restrict__ Vp, int kvs,
        unsigned short* __restrict__ Op)
{
    __shared__ unsigned short Ks[128 * 72];
    __shared__ unsigned short Qs[64 * 72];
    __shared__ unsigned short Vt[64 * 136];
    __shared__ unsigned short Ps[64 * 136];
    const int bh    = blockIdx.x >> 1;
    const int qbase = (blockIdx.x & 1) << 6;
    const int brow  = (bh >> 3) * SEQ;
    const int hoff  = (bh & 7) * DHEAD;
    const int tid = threadIdx.x, lane = tid & 63, wid = tid >> 6;

    #pragma unroll
    for (int it = 0; it < 4; ++it) {
        int idx = it * 256 + tid;
        int row = idx >> 3;
        int c8  = (idx & 7) << 3;
        *(uint4*)&Ks[row * 72 + c8] =
            *(const uint4*)(Kp + (size_t)(brow + row) * kvs + hoff + c8);
        uint4 vu = *(const uint4*)(Vp + (size_t)(brow + row) * kvs + hoff + c8);
        unsigned arr[4] = {vu.x, vu.y, vu.z, vu.w};
        #pragma unroll
        for (int j = 0; j < 8; ++j)
            Vt[(c8 + j) * 136 + row] = (unsigned short)(arr[j >> 1] >> ((j & 1) * 16));
    }
    #pragma unroll
    for (int it = 0; it < 2; ++it) {
        int idx = it * 256 + tid;
        int row = idx >> 3;
        int c8  = (idx & 7) << 3;
        *(uint4*)&Qs[row * 72 + c8] =
            *(const uint4*)(Qp + (size_t)(brow + qbase + row) * qs + hoff + c8);
    }
    __syncthreads();
    attn_phase<CAUSAL>(Ks, Vt, Qs, Ps, qbase, brow, hoff, Op, lane, wid);
}

// ---------------- fused Q-proj + cross-attention ----------------------------
__global__ __launch_bounds__(256) void xattn_kernel(
        const unsigned short* __restrict__ Hb,   // [1024][512] dec LN'd
        const unsigned short* __restrict__ Wq,   // [512][512] q^T (first block)
        const float* __restrict__ bias,          // [1536] (q at offset 0)
        const unsigned short* __restrict__ KV,   // [1024][1024]
        unsigned short* __restrict__ Op)
{
    __shared__ __align__(16) char lds[63488];
    unsigned short* Ks  = (unsigned short*)(lds);
    unsigned short* Vt  = (unsigned short*)(lds + 18432);
    unsigned short* Qs  = (unsigned short*)(lds + 35840);
    unsigned short* Ps  = (unsigned short*)(lds + 46080);
    unsigned short* Hs  = (unsigned short*)(lds + 35840);
    unsigned short* Wqs = (unsigned short*)(lds + 46080);

    const int bh = blockIdx.x >> 1;
    const int qbase = (blockIdx.x & 1) << 6;
    const int h = bh & 7;
    const int brow = (bh >> 3) * SEQ;
    const int hoff = h * DHEAD;
    const int tid = threadIdx.x, lane = tid & 63, wid = tid >> 6;
    const int fr = lane & 15, fg = lane >> 4;

    #pragma unroll
    for (int it = 0; it < 4; ++it) {
        int idx = it * 256 + tid;
        int row = idx >> 3, c8 = (idx & 7) << 3;
        const unsigned short* kvrow = KV + (size_t)(brow + row) * 1024 + hoff;
        *(uint4*)&Ks[row * 72 + c8] = *(const uint4*)(kvrow + c8);
        uint4 vu = *(const uint4*)(kvrow + 512 + c8);
        unsigned arr[4] = {vu.x, vu.y, vu.z, vu.w};
        #pragma unroll
        for (int j = 0; j < 8; ++j)
            Vt[(c8 + j) * 136 + row] = (unsigned short)(arr[j >> 1] >> ((j & 1) * 16));
    }
    f32x4 accQ[4];
    #pragma unroll
    for (int n = 0; n < 4; ++n) accQ[n] = (f32x4){0.f, 0.f, 0.f, 0.f};
    for (int kt = 0; kt < 8; ++kt) {
        #pragma unroll
        for (int it = 0; it < 2; ++it) {
            int idx = it * 256 + tid;
            int row = idx >> 3, c8 = (idx & 7) << 3;
            *(uint4*)&Hs[row * 72 + c8] =
                *(const uint4*)(Hb + (size_t)(brow + qbase + row) * 512 + kt * 64 + c8);
            *(uint4*)&Wqs[row * 72 + c8] =
                *(const uint4*)(Wq + (size_t)(hoff + row) * 512 + kt * 64 + c8);
        }
        __syncthreads();
        #pragma unroll
        for (int s = 0; s < 2; ++s) {
            int fk = s * 32 + fg * 8;
            bf16x8 hq = *(const bf16x8*)&Hs[(wid * 16 + fr) * 72 + fk];
            #pragma unroll
            for (int n = 0; n < 4; ++n) {
                bf16x8 wq = *(const bf16x8*)&Wqs[(n * 16 + fr) * 72 + fk];
                accQ[n] = __builtin_amdgcn_mfma_f32_16x16x32_bf16(hq, wq, accQ[n], 0, 0, 0);
            }
        }
        __syncthreads();
    }
    #pragma unroll
    for (int n = 0; n < 4; ++n) {
        int d = n * 16 + fr;
        float bq = bias[hoff + d];
        #pragma unroll
        for (int r = 0; r < 4; ++r) {
            int ql = wid * 16 + fg * 4 + r;
            Qs[ql * 72 + d] = f2b(accQ[n][r] + bq);
        }
    }
    __syncthreads();
    attn_phase<0>(Ks, Vt, Qs, Ps, qbase, brow, hoff, Op, lane, wid);
}

// ---------------------------------------------------------------------------
extern "C" void kernel_launch(void* const* d_in, const int* in_sizes, int n_in,
                              void* d_out, int out_size, void* d_ws, size_t ws_size,
                              hipStream_t stream)
{
    const int*   src       = (const int*)d_in[0];
    const int*   tgt       = (const int*)d_in[1];
    const float* src_emb   = (const float*)d_in[2];
    const float* tgt_emb   = (const float*)d_in[3];
    const float* enc_qkv_w = (const float*)d_in[4];
    const float* enc_qkv_b = (const float*)d_in[5];
    const float* enc_o_w   = (const float*)d_in[6];
    const float* enc_o_b   = (const float*)d_in[7];
    const float* enc_ff_w1 = (const float*)d_in[8];
    const float* enc_ff_b1 = (const float*)d_in[9];
    const float* enc_ff_w2 = (const float*)d_in[10];
    const float* enc_ff_b2 = (const float*)d_in[11];
    const float* enc_ln_g  = (const float*)d_in[12];
    const float* enc_ln_b  = (const float*)d_in[13];
    const float* enc_fg    = (const float*)d_in[14];
    const float* enc_fb    = (const float*)d_in[15];
    const float* dec_sqkv_w = (const float*)d_in[16];
    const float* dec_sqkv_b = (const float*)d_in[17];
    const float* dec_so_w   = (const float*)d_in[18];
    const float* dec_so_b   = (const float*)d_in[19];
    const float* dec_cqkv_w = (const float*)d_in[20];
    const float* dec_cqkv_b = (const float*)d_in[21];
    const float* dec_co_w   = (const float*)d_in[22];
    const float* dec_co_b   = (const float*)d_in[23];
    const float* dec_ff_w1  = (const float*)d_in[24];
    const float* dec_ff_b1  = (const float*)d_in[25];
    const float* dec_ff_w2  = (const float*)d_in[26];
    const float* dec_ff_b2  = (const float*)d_in[27];
    const float* dec_ln_g   = (const float*)d_in[28];
    const float* dec_ln_b   = (const float*)d_in[29];
    const float* dec_fg     = (const float*)d_in[30];
    const float* dec_fb     = (const float*)d_in[31];

    // ---- workspace carve ----
    unsigned short* wp = (unsigned short*)d_ws;
    unsigned short* WencQKV  = wp; wp += (size_t)6 * 786432;
    unsigned short* WencO    = wp; wp += (size_t)6 * 262144;
    unsigned short* WencF1   = wp; wp += (size_t)6 * 1048576;
    unsigned short* WencF2   = wp; wp += (size_t)6 * 1048576;
    unsigned short* WdecSQKV = wp; wp += (size_t)6 * 786432;
    unsigned short* WdecSO   = wp; wp += (size_t)6 * 262144;
    unsigned short* WdecCQKV = wp; wp += (size_t)6 * 786432;
    unsigned short* WdecCO   = wp; wp += (size_t)6 * 262144;
    unsigned short* WdecF1   = wp; wp += (size_t)6 * 1048576;
    unsigned short* WdecF2   = wp; wp += (size_t)6 * 1048576;
    unsigned short* Hb   = wp; wp += ROWS * D;
    unsigned short* QKVb = wp; wp += ROWS * 3 * D;
    unsigned short* CKVall = wp; wp += (size_t)6 * ROWS * 1024;
    unsigned short* ATTb = wp; wp += ROWS * D;
    unsigned short* F1b  = wp; wp += ROWS * DFF;
    unsigned short* MEMb = wp; wp += ROWS * D;
    float* X  = (float*)wp;  wp += ROWS * D * 2;   // fp32 encoder residual
    float* X2 = (float*)wp;  wp += ROWS * D * 2;   // fp32 decoder residual

    // ---- batched weight transposes: 3 launches (ALL 6 square groups) ----
    {
        TMulti mA = {{ {enc_qkv_w,  WencQKV,  18},
                       {enc_o_w,    WencO,     6},
                       {dec_sqkv_w, WdecSQKV, 18},
                       {dec_so_w,   WdecSO,    6},
                       {dec_cqkv_w, WdecCQKV, 18},
                       {dec_co_w,   WdecCO,    6} }};
        transpose_multi_kernel<<<dim3(16, 16, 72), 256, 0, stream>>>(mA, 512, 512);
        TMulti mB = {{ {enc_ff_w1, WencF1, 6},
                       {dec_ff_w1, WdecF1, 6},
                       {nullptr, nullptr, 1 << 30}, {nullptr, nullptr, 1 << 30},
                       {nullptr, nullptr, 1 << 30}, {nullptr, nullptr, 1 << 30} }};
        transpose_multi_kernel<<<dim3(64, 16, 12), 256, 0, stream>>>(mB, 512, 2048);
        TMulti mC = {{ {enc_ff_w2, WencF2, 6},
                       {dec_ff_w2, WdecF2, 6},
                       {nullptr, nullptr, 1 << 30}, {nullptr, nullptr, 1 << 30},
                       {nullptr, nullptr, 1 << 30}, {nullptr, nullptr, 1 << 30} }};
        transpose_multi_kernel<<<dim3(16, 64, 12), 256, 0, stream>>>(mC, 2048, 512);
    }

    // ---- both embeddings upfront (z=2) ----
    embed_pe_kernel<<<dim3(2048, 1, 2), 256, 0, stream>>>(src, tgt, src_emb, tgt_emb, X, X2);

    // ---------------- encoder ----------------
    for (int i = 0; i < LAYERS; ++i) {
        ln_kernel<1><<<256, 256, 0, stream>>>(X, enc_ln_g + (size_t)(i*2+0)*D, enc_ln_b + (size_t)(i*2+0)*D, Hb);
        mgemm32_kernel<0,0,1><<<dim3(24,32), 256, 0, stream>>>(Hb, WencQKV + (size_t)i*786432,
                enc_qkv_b + (size_t)i*1536, nullptr, QKVb, 1536, 512);
        attn_kernel<0><<<128, 256, 0, stream>>>(QKVb, 1536, QKVb + 512, QKVb + 1024, 1536, ATTb);
        mgemm32_kernel<1,0,0><<<dim3(8,32), 256, 0, stream>>>(ATTb, WencO + (size_t)i*262144,
                enc_o_b + (size_t)i*512, X, X, 512, 512);
        ln_kernel<1><<<256, 256, 0, stream>>>(X, enc_ln_g + (size_t)(i*2+1)*D, enc_ln_b + (size_t)(i*2+1)*D, Hb);
        mgemm32_kernel<0,1,1><<<dim3(32,32), 256, 0, stream>>>(Hb, WencF1 + (size_t)i*1048576,
                enc_ff_b1 + (size_t)i*DFF, nullptr, F1b, DFF, 512);
        mgemm32_kernel<1,0,0><<<dim3(8,32), 256, 0, stream>>>(F1b, WencF2 + (size_t)i*1048576,
                enc_ff_b2 + (size_t)i*512, X, X, 512, DFF);
    }
    ln_kernel<1><<<256, 256, 0, stream>>>(X, enc_fg, enc_fb, MEMb);

    // ---- all 6 decoder layers' cross K/V: one batched GEMM (BM=64 kernel) --
    mgemm_kernel<0,0,1><<<dim3(16,16,6), 256, 0, stream>>>(MEMb, WdecCQKV + 262144,
            dec_cqkv_b + 512, nullptr, CKVall, 1024, 512,
            0, 786432, 1536, (long)ROWS * 1024);

    // ---------------- decoder ----------------
    for (int i = 0; i < LAYERS; ++i) {
        ln_kernel<1><<<256, 256, 0, stream>>>(X2, dec_ln_g + (size_t)(i*3+0)*D, dec_ln_b + (size_t)(i*3+0)*D, Hb);
        mgemm32_kernel<0,0,1><<<dim3(24,32), 256, 0, stream>>>(Hb, WdecSQKV + (size_t)i*786432,
                dec_sqkv_b + (size_t)i*1536, nullptr, QKVb, 1536, 512);
        attn_kernel<1><<<128, 256, 0, stream>>>(QKVb, 1536, QKVb + 512, QKVb + 1024, 1536, ATTb);
        mgemm32_kernel<1,0,0><<<dim3(8,32), 256, 0, stream>>>(ATTb, WdecSO + (size_t)i*262144,
                dec_so_b + (size_t)i*512, X2, X2, 512, 512);
        ln_kernel<1><<<256, 256, 0, stream>>>(X2, dec_ln_g + (size_t)(i*3+1)*D, dec_ln_b + (size_t)(i*3+1)*D, Hb);
        xattn_kernel<<<128, 256, 0, stream>>>(Hb, WdecCQKV + (size_t)i*786432,
                dec_cqkv_b + (size_t)i*1536, CKVall + (size_t)i*ROWS*1024, ATTb);
        mgemm32_kernel<1,0,0><<<dim3(8,32), 256, 0, stream>>>(ATTb, WdecCO + (size_t)i*262144,
                dec_co_b + (size_t)i*512, X2, X2, 512, 512);
        ln_kernel<1><<<256, 256, 0, stream>>>(X2, dec_ln_g + (size_t)(i*3+2)*D, dec_ln_b + (size_t)(i*3+2)*D, Hb);
        mgemm32_kernel<0,1,1><<<dim3(32,32), 256, 0, stream>>>(Hb, WdecF1 + (size_t)i*1048576,
                dec_ff_b1 + (size_t)i*DFF, nullptr, F1b, DFF, 512);
        mgemm32_kernel<1,0,0><<<dim3(8,32), 256, 0, stream>>>(F1b, WdecF2 + (size_t)i*1048576,
                dec_ff_b2 + (size_t)i*512, X2, X2, 512, DFF);
    }
    ln_kernel<0><<<256, 256, 0, stream>>>(X2, dec_fg, dec_fb, d_out);
}

// Round 16
// 748.563 us; speedup vs baseline: 1.0142x; 1.0142x over previous
//
#include <hip/hip_runtime.h>
#include <hip/hip_bf16.h>
#include <math.h>

#define D 512
#define NH 8
#define DHEAD 64
#define LAYERS 6
#define DFF 2048
#define BATCH 8
#define SEQ 128
#define ROWS (BATCH * SEQ)   // 1024

typedef float f32x4 __attribute__((ext_vector_type(4)));
typedef short bf16x8 __attribute__((ext_vector_type(8)));

__device__ __forceinline__ unsigned short f2b(float x) {
    return __builtin_bit_cast(unsigned short, __float2bfloat16(x));
}

// ---------------- embedding + positional encoding (both streams, z=2) -------
__global__ __launch_bounds__(256) void embed_pe_kernel(
        const int* __restrict__ tok0, const int* __restrict__ tok1,
        const float* __restrict__ emb0, const float* __restrict__ emb1,
        float* __restrict__ out0, float* __restrict__ out1)
{
    const int z = blockIdx.z;
    const int* tok = z ? tok1 : tok0;
    const float* emb = z ? emb1 : emb0;
    float* out = z ? out1 : out0;
    int i = blockIdx.x * 256 + threadIdx.x;
    int bs = i >> 9;
    int d  = i & 511;
    int s  = bs & (SEQ - 1);
    int tk = tok[bs];
    float dv  = expf(-(float)(d & ~1) * (9.210340371976184f / 512.0f));
    float arg = (float)s * dv;
    float pe  = (d & 1) ? cosf(arg) : sinf(arg);
    out[i] = emb[(size_t)tk * D + d] * 22.627416997969522f + pe;
}

// ---------------- batched multi-source transpose + fp32->bf16 ---------------
struct TSeg { const float* src; unsigned short* dst; int cnt; };
struct TMulti { TSeg seg[6]; };

__global__ __launch_bounds__(256) void transpose_multi_kernel(TMulti m, int R, int C)
{
    __shared__ float t[32][33];
    int z = blockIdx.z, s = 0;
    while (z >= m.seg[s].cnt) { z -= m.seg[s].cnt; ++s; }
    const float* src = m.seg[s].src + (size_t)z * R * C;
    unsigned short* dst = m.seg[s].dst + (size_t)z * R * C;
    const int r0 = blockIdx.y << 5, c0 = blockIdx.x << 5;
    const int tid = threadIdx.x;
    const int rr = tid >> 3, cc = (tid & 7) << 2;
    float4 v = *(const float4*)(src + (size_t)(r0 + rr) * C + c0 + cc);
    t[rr][cc] = v.x; t[rr][cc + 1] = v.y; t[rr][cc + 2] = v.z; t[rr][cc + 3] = v.w;
    __syncthreads();
    const int oc = tid >> 3, or4 = (tid & 7) << 2;
    ushort4 o;
    o.x = f2b(t[or4 + 0][oc]);
    o.y = f2b(t[or4 + 1][oc]);
    o.z = f2b(t[or4 + 2][oc]);
    o.w = f2b(t[or4 + 3][oc]);
    *(ushort4*)(dst + (size_t)(c0 + oc) * R + r0 + or4) = o;
}

// ---------------- LayerNorm: one wave per row of 512 ------------------------
template<int OUT_BF16>
__global__ __launch_bounds__(256) void ln_kernel(const float* __restrict__ x,
        const float* __restrict__ g, const float* __restrict__ bta,
        void* __restrict__ outp)
{
    int lane = threadIdx.x & 63;
    int row  = (blockIdx.x << 2) + (threadIdx.x >> 6);
    const float* xr = x + (size_t)row * D;
    int c = lane * 8;
    float4 v0 = *(const float4*)(xr + c);
    float4 v1 = *(const float4*)(xr + c + 4);
    float s  = v0.x + v0.y + v0.z + v0.w + v1.x + v1.y + v1.z + v1.w;
    float sq = v0.x*v0.x + v0.y*v0.y + v0.z*v0.z + v0.w*v0.w
             + v1.x*v1.x + v1.y*v1.y + v1.z*v1.z + v1.w*v1.w;
    #pragma unroll
    for (int o = 32; o; o >>= 1) {
        s  += __shfl_xor(s, o);
        sq += __shfl_xor(sq, o);
    }
    float mean = s * (1.0f / D);
    float var  = sq * (1.0f / D) - mean * mean;
    float inv  = rsqrtf(var + 1e-6f);
    float4 g0 = *(const float4*)(g + c),   g1 = *(const float4*)(g + c + 4);
    float4 b0 = *(const float4*)(bta + c), b1 = *(const float4*)(bta + c + 4);
    float4 o0, o1;
    o0.x = g0.x * (v0.x - mean) * inv + b0.x;
    o0.y = g0.y * (v0.y - mean) * inv + b0.y;
    o0.z = g0.z * (v0.z - mean) * inv + b0.z;
    o0.w = g0.w * (v0.w - mean) * inv + b0.w;
    o1.x = g1.x * (v1.x - mean) * inv + b1.x;
    o1.y = g1.y * (v1.y - mean) * inv + b1.y;
    o1.z = g1.z * (v1.z - mean) * inv + b1.z;
    o1.w = g1.w * (v1.w - mean) * inv + b1.w;
    if (OUT_BF16) {
        unsigned short* orow = (unsigned short*)outp + (size_t)row * D + c;
        uint4 o;
        o.x = (unsigned int)f2b(o0.x) | ((unsigned int)f2b(o0.y) << 16);
        o.y = (unsigned int)f2b(o0.z) | ((unsigned int)f2b(o0.w) << 16);
        o.z = (unsigned int)f2b(o1.x) | ((unsigned int)f2b(o1.y) << 16);
        o.w = (unsigned int)f2b(o1.z) | ((unsigned int)f2b(o1.w) << 16);
        *(uint4*)orow = o;
    } else {
        float* orow = (float*)outp + (size_t)row * D + c;
        *(float4*)(orow)     = o0;
        *(float4*)(orow + 4) = o1;
    }
}

// ---------------- bf16 MFMA GEMM (dbuf, BK=64, z-batch) ---------------------
template<int RESID, int RELU, int OUT_BF16>
__global__ __launch_bounds__(256) void mgemm_kernel(
        const unsigned short* __restrict__ A,
        const unsigned short* __restrict__ Wt,
        const float* __restrict__ bias,
        const float* __restrict__ Rp,
        void* __restrict__ Cout,
        int N, int K,
        long aZ, long wZ, long bZ, long cZ)
{
    __shared__ unsigned short As[2][64][72];
    __shared__ unsigned short Bs[2][64][72];
    const long z = blockIdx.z;
    const unsigned short* Ab = A  + z * aZ;
    const unsigned short* Wb = Wt + z * wZ;
    const float* biasb = bias + z * bZ;
    const int tid  = threadIdx.x;
    const int lane = tid & 63, wid = tid >> 6;
    const int wm = wid >> 1, wn = wid & 1;
    const int bm = blockIdx.y << 6, bn = blockIdx.x << 6;
    const int srow = tid >> 2, sk = (tid & 3) << 4;
    const unsigned short* Ag = Ab + (size_t)(bm + srow) * K + sk;
    const unsigned short* Bg = Wb + (size_t)(bn + srow) * K + sk;
    const int fr = lane & 15;
    const int fk = (lane >> 4) << 3;
    f32x4 acc[2][2];
    #pragma unroll
    for (int i = 0; i < 2; ++i)
        #pragma unroll
        for (int j = 0; j < 2; ++j)
            acc[i][j] = (f32x4){0.f, 0.f, 0.f, 0.f};

    uint4 a0 = *(const uint4*)Ag, a1 = *(const uint4*)(Ag + 8);
    uint4 b0 = *(const uint4*)Bg, b1 = *(const uint4*)(Bg + 8);
    const int T = K >> 6;
    for (int t = 0; t < T; ++t) {
        const int p = t & 1;
        *(uint4*)&As[p][srow][sk]     = a0;
        *(uint4*)&As[p][srow][sk + 8] = a1;
        *(uint4*)&Bs[p][srow][sk]     = b0;
        *(uint4*)&Bs[p][srow][sk + 8] = b1;
        if (t + 1 < T) {
            Ag += 64; Bg += 64;
            a0 = *(const uint4*)Ag; a1 = *(const uint4*)(Ag + 8);
            b0 = *(const uint4*)Bg; b1 = *(const uint4*)(Bg + 8);
        }
        __syncthreads();
        #pragma unroll
        for (int s = 0; s < 2; ++s) {
            bf16x8 af0 = *(const bf16x8*)&As[p][wm * 32 + fr][s * 32 + fk];
            bf16x8 af1 = *(const bf16x8*)&As[p][wm * 32 + 16 + fr][s * 32 + fk];
            bf16x8 bf0 = *(const bf16x8*)&Bs[p][wn * 32 + fr][s * 32 + fk];
            bf16x8 bf1 = *(const bf16x8*)&Bs[p][wn * 32 + 16 + fr][s * 32 + fk];
            acc[0][0] = __builtin_amdgcn_mfma_f32_16x16x32_bf16(af0, bf0, acc[0][0], 0, 0, 0);
            acc[0][1] = __builtin_amdgcn_mfma_f32_16x16x32_bf16(af0, bf1, acc[0][1], 0, 0, 0);
            acc[1][0] = __builtin_amdgcn_mfma_f32_16x16x32_bf16(af1, bf0, acc[1][0], 0, 0, 0);
            acc[1][1] = __builtin_amdgcn_mfma_f32_16x16x32_bf16(af1, bf1, acc[1][1], 0, 0, 0);
        }
    }
    const int cr   = (lane >> 4) << 2;
    const int ccol = lane & 15;
    #pragma unroll
    for (int i = 0; i < 2; ++i)
        #pragma unroll
        for (int j = 0; j < 2; ++j) {
            int col = bn + wn * 32 + j * 16 + ccol;
            float bsv = biasb[col];
            #pragma unroll
            for (int r = 0; r < 4; ++r) {
                int row = bm + wm * 32 + i * 16 + cr + r;
                float v = acc[i][j][r] + bsv;
                if (RESID) v += Rp[(size_t)row * N + col];
                if (RELU)  v = fmaxf(v, 0.f);
                if (OUT_BF16) ((unsigned short*)Cout + z * cZ)[(size_t)row * N + col] = f2b(v);
                else          ((float*)Cout)[(size_t)row * N + col] = v;
            }
        }
}

// ============ shared attention phase =========================================
template<int CAUSAL>
__device__ __forceinline__ void attn_phase(
        const unsigned short* Ks, const unsigned short* Vt,
        const unsigned short* Qs, unsigned short* Ps,
        int qbase, int brow, int hoff, unsigned short* __restrict__ Op,
        int lane, int wid)
{
    const int fr = lane & 15, fg = lane >> 4;
    f32x4 accs[8];
    #pragma unroll
    for (int kf = 0; kf < 8; ++kf) accs[kf] = (f32x4){0.f, 0.f, 0.f, 0.f};
    bf16x8 aq0 = *(const bf16x8*)&Qs[(wid * 16 + fr) * 72 + fg * 8];
    bf16x8 aq1 = *(const bf16x8*)&Qs[(wid * 16 + fr) * 72 + 32 + fg * 8];
    #pragma unroll
    for (int kf = 0; kf < 8; ++kf) {
        bf16x8 bk0 = *(const bf16x8*)&Ks[(kf * 16 + fr) * 72 + fg * 8];
        bf16x8 bk1 = *(const bf16x8*)&Ks[(kf * 16 + fr) * 72 + 32 + fg * 8];
        accs[kf] = __builtin_amdgcn_mfma_f32_16x16x32_bf16(aq0, bk0, accs[kf], 0, 0, 0);
        accs[kf] = __builtin_amdgcn_mfma_f32_16x16x32_bf16(aq1, bk1, accs[kf], 0, 0, 0);
    }
    const float SC = 0.125f * 1.44269504f;
    float linv[4];
    #pragma unroll
    for (int r = 0; r < 4; ++r) {
        int qrow = qbase + wid * 16 + fg * 4 + r;
        float sv[8];
        #pragma unroll
        for (int kf = 0; kf < 8; ++kf) {
            float s = accs[kf][r] * SC;
            if (CAUSAL) {
                int key = kf * 16 + fr;
                if (key > qrow) s = -1e30f;
            }
            sv[kf] = s;
        }
        float m = sv[0];
        #pragma unroll
        for (int kf = 1; kf < 8; ++kf) m = fmaxf(m, sv[kf]);
        #pragma unroll
        for (int o = 1; o < 16; o <<= 1) m = fmaxf(m, __shfl_xor(m, o));
        float l = 0.f;
        #pragma unroll
        for (int kf = 0; kf < 8; ++kf) {
            float p = exp2f(sv[kf] - m);
            l += p;
            Ps[(wid * 16 + fg * 4 + r) * 136 + kf * 16 + fr] = f2b(p);
        }
        #pragma unroll
        for (int o = 1; o < 16; o <<= 1) l += __shfl_xor(l, o);
        linv[r] = 1.f / l;
    }
    f32x4 acco[4];
    #pragma unroll
    for (int df = 0; df < 4; ++df) acco[df] = (f32x4){0.f, 0.f, 0.f, 0.f};
    #pragma unroll
    for (int ks = 0; ks < 4; ++ks) {
        bf16x8 pa = *(const bf16x8*)&Ps[(wid * 16 + fr) * 136 + ks * 32 + fg * 8];
        #pragma unroll
        for (int df = 0; df < 4; ++df) {
            bf16x8 vb = *(const bf16x8*)&Vt[(df * 16 + fr) * 136 + ks * 32 + fg * 8];
            acco[df] = __builtin_amdgcn_mfma_f32_16x16x32_bf16(pa, vb, acco[df], 0, 0, 0);
        }
    }
    #pragma unroll
    for (int df = 0; df < 4; ++df)
        #pragma unroll
        for (int r = 0; r < 4; ++r) {
            int qrow = qbase + wid * 16 + fg * 4 + r;
            Op[(size_t)(brow + qrow) * D + hoff + df * 16 + fr] = f2b(acco[df][r] * linv[r]);
        }
}

// ---------------- standalone attention (proven) -----------------------------
template<int CAUSAL>
__global__ __launch_bounds__(256) void attn_kernel(
        const unsigned short* __restrict__ Qp, int qs,
        const unsigned short* __restrict__ Kp,
        const unsigned short* __restrict__ Vp, int kvs,
        unsigned short* __restrict__ Op)
{
    __shared__ unsigned short Ks[128 * 72];
    __shared__ unsigned short Qs[64 * 72];
    __shared__ unsigned short Vt[64 * 136];
    __shared__ unsigned short Ps[64 * 136];
    const int bh    = blockIdx.x >> 1;
    const int qbase = (blockIdx.x & 1) << 6;
    const int brow  = (bh >> 3) * SEQ;
    const int hoff  = (bh & 7) * DHEAD;
    const int tid = threadIdx.x, lane = tid & 63, wid = tid >> 6;

    #pragma unroll
    for (int it = 0; it < 4; ++it) {
        int idx = it * 256 + tid;
        int row = idx >> 3;
        int c8  = (idx & 7) << 3;
        *(uint4*)&Ks[row * 72 + c8] =
            *(const uint4*)(Kp + (size_t)(brow + row) * kvs + hoff + c8);
        uint4 vu = *(const uint4*)(Vp + (size_t)(brow + row) * kvs + hoff + c8);
        unsigned arr[4] = {vu.x, vu.y, vu.z, vu.w};
        #pragma unroll
        for (int j = 0; j < 8; ++j)
            Vt[(c8 + j) * 136 + row] = (unsigned short)(arr[j >> 1] >> ((j & 1) * 16));
    }
    #pragma unroll
    for (int it = 0; it < 2; ++it) {
        int idx = it * 256 + tid;
        int row = idx >> 3;
        int c8  = (idx & 7) << 3;
        *(uint4*)&Qs[row * 72 + c8] =
            *(const uint4*)(Qp + (size_t)(brow + qbase + row) * qs + hoff + c8);
    }
    __syncthreads();
    attn_phase<CAUSAL>(Ks, Vt, Qs, Ps, qbase, brow, hoff, Op, lane, wid);
}

// ---------------- fused Q-proj + cross-attention ----------------------------
__global__ __launch_bounds__(256) void xattn_kernel(
        const unsigned short* __restrict__ Hb,   // [1024][512] dec LN'd
        const unsigned short* __restrict__ Wq,   // [512][512] q^T (first block)
        const float* __restrict__ bias,          // [1536] (q at offset 0)
        const unsigned short* __restrict__ KV,   // [1024][1024]
        unsigned short* __restrict__ Op)
{
    __shared__ __align__(16) char lds[63488];
    unsigned short* Ks  = (unsigned short*)(lds);
    unsigned short* Vt  = (unsigned short*)(lds + 18432);
    unsigned short* Qs  = (unsigned short*)(lds + 35840);
    unsigned short* Ps  = (unsigned short*)(lds + 46080);
    unsigned short* Hs  = (unsigned short*)(lds + 35840);
    unsigned short* Wqs = (unsigned short*)(lds + 46080);

    const int bh = blockIdx.x >> 1;
    const int qbase = (blockIdx.x & 1) << 6;
    const int h = bh & 7;
    const int brow = (bh >> 3) * SEQ;
    const int hoff = h * DHEAD;
    const int tid = threadIdx.x, lane = tid & 63, wid = tid >> 6;
    const int fr = lane & 15, fg = lane >> 4;

    #pragma unroll
    for (int it = 0; it < 4; ++it) {
        int idx = it * 256 + tid;
        int row = idx >> 3, c8 = (idx & 7) << 3;
        const unsigned short* kvrow = KV + (size_t)(brow + row) * 1024 + hoff;
        *(uint4*)&Ks[row * 72 + c8] = *(const uint4*)(kvrow + c8);
        uint4 vu = *(const uint4*)(kvrow + 512 + c8);
        unsigned arr[4] = {vu.x, vu.y, vu.z, vu.w};
        #pragma unroll
        for (int j = 0; j < 8; ++j)
            Vt[(c8 + j) * 136 + row] = (unsigned short)(arr[j >> 1] >> ((j & 1) * 16));
    }
    f32x4 accQ[4];
    #pragma unroll
    for (int n = 0; n < 4; ++n) accQ[n] = (f32x4){0.f, 0.f, 0.f, 0.f};
    for (int kt = 0; kt < 8; ++kt) {
        #pragma unroll
        for (int it = 0; it < 2; ++it) {
            int idx = it * 256 + tid;
            int row = idx >> 3, c8 = (idx & 7) << 3;
            *(uint4*)&Hs[row * 72 + c8] =
                *(const uint4*)(Hb + (size_t)(brow + qbase + row) * 512 + kt * 64 + c8);
            *(uint4*)&Wqs[row * 72 + c8] =
                *(const uint4*)(Wq + (size_t)(hoff + row) * 512 + kt * 64 + c8);
        }
        __syncthreads();
        #pragma unroll
        for (int s = 0; s < 2; ++s) {
            int fk = s * 32 + fg * 8;
            bf16x8 hq = *(const bf16x8*)&Hs[(wid * 16 + fr) * 72 + fk];
            #pragma unroll
            for (int n = 0; n < 4; ++n) {
                bf16x8 wq = *(const bf16x8*)&Wqs[(n * 16 + fr) * 72 + fk];
                accQ[n] = __builtin_amdgcn_mfma_f32_16x16x32_bf16(hq, wq, accQ[n], 0, 0, 0);
            }
        }
        __syncthreads();
    }
    #pragma unroll
    for (int n = 0; n < 4; ++n) {
        int d = n * 16 + fr;
        float bq = bias[hoff + d];
        #pragma unroll
        for (int r = 0; r < 4; ++r) {
            int ql = wid * 16 + fg * 4 + r;
            Qs[ql * 72 + d] = f2b(accQ[n][r] + bq);
        }
    }
    __syncthreads();
    attn_phase<0>(Ks, Vt, Qs, Ps, qbase, brow, hoff, Op, lane, wid);
}

// ---------------------------------------------------------------------------
extern "C" void kernel_launch(void* const* d_in, const int* in_sizes, int n_in,
                              void* d_out, int out_size, void* d_ws, size_t ws_size,
                              hipStream_t stream)
{
    const int*   src       = (const int*)d_in[0];
    const int*   tgt       = (const int*)d_in[1];
    const float* src_emb   = (const float*)d_in[2];
    const float* tgt_emb   = (const float*)d_in[3];
    const float* enc_qkv_w = (const float*)d_in[4];
    const float* enc_qkv_b = (const float*)d_in[5];
    const float* enc_o_w   = (const float*)d_in[6];
    const float* enc_o_b   = (const float*)d_in[7];
    const float* enc_ff_w1 = (const float*)d_in[8];
    const float* enc_ff_b1 = (const float*)d_in[9];
    const float* enc_ff_w2 = (const float*)d_in[10];
    const float* enc_ff_b2 = (const float*)d_in[11];
    const float* enc_ln_g  = (const float*)d_in[12];
    const float* enc_ln_b  = (const float*)d_in[13];
    const float* enc_fg    = (const float*)d_in[14];
    const float* enc_fb    = (const float*)d_in[15];
    const float* dec_sqkv_w = (const float*)d_in[16];
    const float* dec_sqkv_b = (const float*)d_in[17];
    const float* dec_so_w   = (const float*)d_in[18];
    const float* dec_so_b   = (const float*)d_in[19];
    const float* dec_cqkv_w = (const float*)d_in[20];
    const float* dec_cqkv_b = (const float*)d_in[21];
    const float* dec_co_w   = (const float*)d_in[22];
    const float* dec_co_b   = (const float*)d_in[23];
    const float* dec_ff_w1  = (const float*)d_in[24];
    const float* dec_ff_b1  = (const float*)d_in[25];
    const float* dec_ff_w2  = (const float*)d_in[26];
    const float* dec_ff_b2  = (const float*)d_in[27];
    const float* dec_ln_g   = (const float*)d_in[28];
    const float* dec_ln_b   = (const float*)d_in[29];
    const float* dec_fg     = (const float*)d_in[30];
    const float* dec_fb     = (const float*)d_in[31];

    // ---- workspace carve ----
    unsigned short* wp = (unsigned short*)d_ws;
    unsigned short* WencQKV  = wp; wp += (size_t)6 * 786432;
    unsigned short* WencO    = wp; wp += (size_t)6 * 262144;
    unsigned short* WencF1   = wp; wp += (size_t)6 * 1048576;
    unsigned short* WencF2   = wp; wp += (size_t)6 * 1048576;
    unsigned short* WdecSQKV = wp; wp += (size_t)6 * 786432;
    unsigned short* WdecSO   = wp; wp += (size_t)6 * 262144;
    unsigned short* WdecCQKV = wp; wp += (size_t)6 * 786432;
    unsigned short* WdecCO   = wp; wp += (size_t)6 * 262144;
    unsigned short* WdecF1   = wp; wp += (size_t)6 * 1048576;
    unsigned short* WdecF2   = wp; wp += (size_t)6 * 1048576;
    unsigned short* Hb   = wp; wp += ROWS * D;
    unsigned short* QKVb = wp; wp += ROWS * 3 * D;
    unsigned short* CKVall = wp; wp += (size_t)6 * ROWS * 1024;
    unsigned short* ATTb = wp; wp += ROWS * D;
    unsigned short* F1b  = wp; wp += ROWS * DFF;
    unsigned short* MEMb = wp; wp += ROWS * D;
    float* X  = (float*)wp;  wp += ROWS * D * 2;   // fp32 encoder residual
    float* X2 = (float*)wp;  wp += ROWS * D * 2;   // fp32 decoder residual

    // ---- batched weight transposes: 3 launches (ALL 6 square groups) ----
    {
        TMulti mA = {{ {enc_qkv_w,  WencQKV,  18},
                       {enc_o_w,    WencO,     6},
                       {dec_sqkv_w, WdecSQKV, 18},
                       {dec_so_w,   WdecSO,    6},
                       {dec_cqkv_w, WdecCQKV, 18},
                       {dec_co_w,   WdecCO,    6} }};
        transpose_multi_kernel<<<dim3(16, 16, 72), 256, 0, stream>>>(mA, 512, 512);
        TMulti mB = {{ {enc_ff_w1, WencF1, 6},
                       {dec_ff_w1, WdecF1, 6},
                       {nullptr, nullptr, 1 << 30}, {nullptr, nullptr, 1 << 30},
                       {nullptr, nullptr, 1 << 30}, {nullptr, nullptr, 1 << 30} }};
        transpose_multi_kernel<<<dim3(64, 16, 12), 256, 0, stream>>>(mB, 512, 2048);
        TMulti mC = {{ {enc_ff_w2, WencF2, 6},
                       {dec_ff_w2, WdecF2, 6},
                       {nullptr, nullptr, 1 << 30}, {nullptr, nullptr, 1 << 30},
                       {nullptr, nullptr, 1 << 30}, {nullptr, nullptr, 1 << 30} }};
        transpose_multi_kernel<<<dim3(16, 64, 12), 256, 0, stream>>>(mC, 2048, 512);
    }

    // ---- both embeddings upfront (z=2) ----
    embed_pe_kernel<<<dim3(2048, 1, 2), 256, 0, stream>>>(src, tgt, src_emb, tgt_emb, X, X2);

    // ---------------- encoder ----------------
    for (int i = 0; i < LAYERS; ++i) {
        ln_kernel<1><<<256, 256, 0, stream>>>(X, enc_ln_g + (size_t)(i*2+0)*D, enc_ln_b + (size_t)(i*2+0)*D, Hb);
        mgemm_kernel<0,0,1><<<dim3(24,16,1), 256, 0, stream>>>(Hb, WencQKV + (size_t)i*786432,
                enc_qkv_b + (size_t)i*1536, nullptr, QKVb, 1536, 512, 0, 0, 0, 0);
        attn_kernel<0><<<128, 256, 0, stream>>>(QKVb, 1536, QKVb + 512, QKVb + 1024, 1536, ATTb);
        mgemm_kernel<1,0,0><<<dim3(8,16,1), 256, 0, stream>>>(ATTb, WencO + (size_t)i*262144,
                enc_o_b + (size_t)i*512, X, X, 512, 512, 0, 0, 0, 0);
        ln_kernel<1><<<256, 256, 0, stream>>>(X, enc_ln_g + (size_t)(i*2+1)*D, enc_ln_b + (size_t)(i*2+1)*D, Hb);
        mgemm_kernel<0,1,1><<<dim3(32,16,1), 256, 0, stream>>>(Hb, WencF1 + (size_t)i*1048576,
                enc_ff_b1 + (size_t)i*DFF, nullptr, F1b, DFF, 512, 0, 0, 0, 0);
        mgemm_kernel<1,0,0><<<dim3(8,16,1), 256, 0, stream>>>(F1b, WencF2 + (size_t)i*1048576,
                enc_ff_b2 + (size_t)i*512, X, X, 512, DFF, 0, 0, 0, 0);
    }
    ln_kernel<1><<<256, 256, 0, stream>>>(X, enc_fg, enc_fb, MEMb);

    // ---- all 6 decoder layers' cross K/V: one batched GEMM ----
    mgemm_kernel<0,0,1><<<dim3(16,16,6), 256, 0, stream>>>(MEMb, WdecCQKV + 262144,
            dec_cqkv_b + 512, nullptr, CKVall, 1024, 512,
            0, 786432, 1536, (long)ROWS * 1024);

    // ---------------- decoder ----------------
    for (int i = 0; i < LAYERS; ++i) {
        ln_kernel<1><<<256, 256, 0, stream>>>(X2, dec_ln_g + (size_t)(i*3+0)*D, dec_ln_b + (size_t)(i*3+0)*D, Hb);
        mgemm_kernel<0,0,1><<<dim3(24,16,1), 256, 0, stream>>>(Hb, WdecSQKV + (size_t)i*786432,
                dec_sqkv_b + (size_t)i*1536, nullptr, QKVb, 1536, 512, 0, 0, 0, 0);
        attn_kernel<1><<<128, 256, 0, stream>>>(QKVb, 1536, QKVb + 512, QKVb + 1024, 1536, ATTb);
        mgemm_kernel<1,0,0><<<dim3(8,16,1), 256, 0, stream>>>(ATTb, WdecSO + (size_t)i*262144,
                dec_so_b + (size_t)i*512, X2, X2, 512, 512, 0, 0, 0, 0);
        ln_kernel<1><<<256, 256, 0, stream>>>(X2, dec_ln_g + (size_t)(i*3+1)*D, dec_ln_b + (size_t)(i*3+1)*D, Hb);
        xattn_kernel<<<128, 256, 0, stream>>>(Hb, WdecCQKV + (size_t)i*786432,
                dec_cqkv_b + (size_t)i*1536, CKVall + (size_t)i*ROWS*1024, ATTb);
        mgemm_kernel<1,0,0><<<dim3(8,16,1), 256, 0, stream>>>(ATTb, WdecCO + (size_t)i*262144,
                dec_co_b + (size_t)i*512, X2, X2, 512, 512, 0, 0, 0, 0);
        ln_kernel<1><<<256, 256, 0, stream>>>(X2, dec_ln_g + (size_t)(i*3+2)*D, dec_ln_b + (size_t)(i*3+2)*D, Hb);
        mgemm_kernel<0,1,1><<<dim3(32,16,1), 256, 0, stream>>>(Hb, WdecF1 + (size_t)i*1048576,
                dec_ff_b1 + (size_t)i*DFF, nullptr, F1b, DFF, 512, 0, 0, 0, 0);
        mgemm_kernel<1,0,0><<<dim3(8,16,1), 256, 0, stream>>>(F1b, WdecF2 + (size_t)i*1048576,
                dec_ff_b2 + (size_t)i*512, X2, X2, 512, DFF, 0, 0, 0, 0);
    }
    ln_kernel<0><<<256, 256, 0, stream>>>(X2, dec_fg, dec_fb, d_out);
}

// Round 17
// 727.031 us; speedup vs baseline: 1.0443x; 1.0296x over previous
//
#include <hip/hip_runtime.h>
#include <hip/hip_bf16.h>
#include <math.h>

#define D 512
#define NH 8
#define DHEAD 64
#define LAYERS 6
#define DFF 2048
#define BATCH 8
#define SEQ 128
#define ROWS (BATCH * SEQ)   // 1024

typedef float f32x4 __attribute__((ext_vector_type(4)));
typedef short bf16x8 __attribute__((ext_vector_type(8)));

__device__ __forceinline__ unsigned short f2b(float x) {
    return __builtin_bit_cast(unsigned short, __float2bfloat16(x));
}

// ---------------- embedding + positional encoding (both streams, z=2) -------
__global__ __launch_bounds__(256) void embed_pe_kernel(
        const int* __restrict__ tok0, const int* __restrict__ tok1,
        const float* __restrict__ emb0, const float* __restrict__ emb1,
        float* __restrict__ out0, float* __restrict__ out1)
{
    const int z = blockIdx.z;
    const int* tok = z ? tok1 : tok0;
    const float* emb = z ? emb1 : emb0;
    float* out = z ? out1 : out0;
    int i = blockIdx.x * 256 + threadIdx.x;
    int bs = i >> 9;
    int d  = i & 511;
    int s  = bs & (SEQ - 1);
    int tk = tok[bs];
    float dv  = expf(-(float)(d & ~1) * (9.210340371976184f / 512.0f));
    float arg = (float)s * dv;
    float pe  = (d & 1) ? cosf(arg) : sinf(arg);
    out[i] = emb[(size_t)tk * D + d] * 22.627416997969522f + pe;
}

// ---------------- batched multi-source transpose + fp32->bf16 ---------------
struct TSeg { const float* src; unsigned short* dst; int cnt; };
struct TMulti { TSeg seg[6]; };

__global__ __launch_bounds__(256) void transpose_multi_kernel(TMulti m, int R, int C)
{
    __shared__ float t[32][33];
    int z = blockIdx.z, s = 0;
    while (z >= m.seg[s].cnt) { z -= m.seg[s].cnt; ++s; }
    const float* src = m.seg[s].src + (size_t)z * R * C;
    unsigned short* dst = m.seg[s].dst + (size_t)z * R * C;
    const int r0 = blockIdx.y << 5, c0 = blockIdx.x << 5;
    const int tid = threadIdx.x;
    const int rr = tid >> 3, cc = (tid & 7) << 2;
    float4 v = *(const float4*)(src + (size_t)(r0 + rr) * C + c0 + cc);
    t[rr][cc] = v.x; t[rr][cc + 1] = v.y; t[rr][cc + 2] = v.z; t[rr][cc + 3] = v.w;
    __syncthreads();
    const int oc = tid >> 3, or4 = (tid & 7) << 2;
    ushort4 o;
    o.x = f2b(t[or4 + 0][oc]);
    o.y = f2b(t[or4 + 1][oc]);
    o.z = f2b(t[or4 + 2][oc]);
    o.w = f2b(t[or4 + 3][oc]);
    *(ushort4*)(dst + (size_t)(c0 + oc) * R + r0 + or4) = o;
}

// ---------------- LayerNorm: one wave per row of 512 ------------------------
template<int OUT_BF16>
__global__ __launch_bounds__(256) void ln_kernel(const float* __restrict__ x,
        const float* __restrict__ g, const float* __restrict__ bta,
        void* __restrict__ outp)
{
    int lane = threadIdx.x & 63;
    int row  = (blockIdx.x << 2) + (threadIdx.x >> 6);
    const float* xr = x + (size_t)row * D;
    int c = lane * 8;
    float4 v0 = *(const float4*)(xr + c);
    float4 v1 = *(const float4*)(xr + c + 4);
    float s  = v0.x + v0.y + v0.z + v0.w + v1.x + v1.y + v1.z + v1.w;
    float sq = v0.x*v0.x + v0.y*v0.y + v0.z*v0.z + v0.w*v0.w
             + v1.x*v1.x + v1.y*v1.y + v1.z*v1.z + v1.w*v1.w;
    #pragma unroll
    for (int o = 32; o; o >>= 1) {
        s  += __shfl_xor(s, o);
        sq += __shfl_xor(sq, o);
    }
    float mean = s * (1.0f / D);
    float var  = sq * (1.0f / D) - mean * mean;
    float inv  = rsqrtf(var + 1e-6f);
    float4 g0 = *(const float4*)(g + c),   g1 = *(const float4*)(g + c + 4);
    float4 b0 = *(const float4*)(bta + c), b1 = *(const float4*)(bta + c + 4);
    float4 o0, o1;
    o0.x = g0.x * (v0.x - mean) * inv + b0.x;
    o0.y = g0.y * (v0.y - mean) * inv + b0.y;
    o0.z = g0.z * (v0.z - mean) * inv + b0.z;
    o0.w = g0.w * (v0.w - mean) * inv + b0.w;
    o1.x = g1.x * (v1.x - mean) * inv + b1.x;
    o1.y = g1.y * (v1.y - mean) * inv + b1.y;
    o1.z = g1.z * (v1.z - mean) * inv + b1.z;
    o1.w = g1.w * (v1.w - mean) * inv + b1.w;
    if (OUT_BF16) {
        unsigned short* orow = (unsigned short*)outp + (size_t)row * D + c;
        uint4 o;
        o.x = (unsigned int)f2b(o0.x) | ((unsigned int)f2b(o0.y) << 16);
        o.y = (unsigned int)f2b(o0.z) | ((unsigned int)f2b(o0.w) << 16);
        o.z = (unsigned int)f2b(o1.x) | ((unsigned int)f2b(o1.y) << 16);
        o.w = (unsigned int)f2b(o1.z) | ((unsigned int)f2b(o1.w) << 16);
        *(uint4*)orow = o;
    } else {
        float* orow = (float*)outp + (size_t)row * D + c;
        *(float4*)(orow)     = o0;
        *(float4*)(orow + 4) = o1;
    }
}

// ---------------- bf16 MFMA GEMM (dbuf, BK=64, depth-2 prefetch, z-batch) ---
// Depth-2 register prefetch: two named reg sets; tile t+2's global load is
// issued when tile t is staged, giving ~2 compute phases of latency cover.
// LDS layout / barriers / math identical to the proven depth-1 version.
template<int RESID, int RELU, int OUT_BF16>
__global__ __launch_bounds__(256) void mgemm_kernel(
        const unsigned short* __restrict__ A,
        const unsigned short* __restrict__ Wt,
        const float* __restrict__ bias,
        const float* __restrict__ Rp,
        void* __restrict__ Cout,
        int N, int K,
        long aZ, long wZ, long bZ, long cZ)
{
    __shared__ unsigned short As[2][64][72];
    __shared__ unsigned short Bs[2][64][72];
    const long z = blockIdx.z;
    const unsigned short* Ab = A  + z * aZ;
    const unsigned short* Wb = Wt + z * wZ;
    const float* biasb = bias + z * bZ;
    const int tid  = threadIdx.x;
    const int lane = tid & 63, wid = tid >> 6;
    const int wm = wid >> 1, wn = wid & 1;
    const int bm = blockIdx.y << 6, bn = blockIdx.x << 6;
    const int srow = tid >> 2, sk = (tid & 3) << 4;
    const unsigned short* Ag = Ab + (size_t)(bm + srow) * K + sk;
    const unsigned short* Bg = Wb + (size_t)(bn + srow) * K + sk;
    const int fr = lane & 15;
    const int fk = (lane >> 4) << 3;
    f32x4 acc[2][2];
    #pragma unroll
    for (int i = 0; i < 2; ++i)
        #pragma unroll
        for (int j = 0; j < 2; ++j)
            acc[i][j] = (f32x4){0.f, 0.f, 0.f, 0.f};

    // T is always even (K = 512 or 2048 -> T = 8 or 32), and >= 2.
    const int T = K >> 6;
    uint4 a0_0 = *(const uint4*)Ag,        a1_0 = *(const uint4*)(Ag + 8);
    uint4 b0_0 = *(const uint4*)Bg,        b1_0 = *(const uint4*)(Bg + 8);
    uint4 a0_1 = *(const uint4*)(Ag + 64), a1_1 = *(const uint4*)(Ag + 72);
    uint4 b0_1 = *(const uint4*)(Bg + 64), b1_1 = *(const uint4*)(Bg + 72);
    const unsigned short* AgN = Ag + 128;
    const unsigned short* BgN = Bg + 128;
    int loaded = 2;

    for (int t = 0; t < T; t += 2) {
        // ---- even step: LDS[0] from set 0 ----
        *(uint4*)&As[0][srow][sk]     = a0_0;
        *(uint4*)&As[0][srow][sk + 8] = a1_0;
        *(uint4*)&Bs[0][srow][sk]     = b0_0;
        *(uint4*)&Bs[0][srow][sk + 8] = b1_0;
        if (loaded < T) {
            a0_0 = *(const uint4*)AgN; a1_0 = *(const uint4*)(AgN + 8);
            b0_0 = *(const uint4*)BgN; b1_0 = *(const uint4*)(BgN + 8);
            AgN += 64; BgN += 64; ++loaded;
        }
        __syncthreads();
        #pragma unroll
        for (int s = 0; s < 2; ++s) {
            bf16x8 af0 = *(const bf16x8*)&As[0][wm * 32 + fr][s * 32 + fk];
            bf16x8 af1 = *(const bf16x8*)&As[0][wm * 32 + 16 + fr][s * 32 + fk];
            bf16x8 bf0 = *(const bf16x8*)&Bs[0][wn * 32 + fr][s * 32 + fk];
            bf16x8 bf1 = *(const bf16x8*)&Bs[0][wn * 32 + 16 + fr][s * 32 + fk];
            acc[0][0] = __builtin_amdgcn_mfma_f32_16x16x32_bf16(af0, bf0, acc[0][0], 0, 0, 0);
            acc[0][1] = __builtin_amdgcn_mfma_f32_16x16x32_bf16(af0, bf1, acc[0][1], 0, 0, 0);
            acc[1][0] = __builtin_amdgcn_mfma_f32_16x16x32_bf16(af1, bf0, acc[1][0], 0, 0, 0);
            acc[1][1] = __builtin_amdgcn_mfma_f32_16x16x32_bf16(af1, bf1, acc[1][1], 0, 0, 0);
        }
        // ---- odd step: LDS[1] from set 1 ----
        *(uint4*)&As[1][srow][sk]     = a0_1;
        *(uint4*)&As[1][srow][sk + 8] = a1_1;
        *(uint4*)&Bs[1][srow][sk]     = b0_1;
        *(uint4*)&Bs[1][srow][sk + 8] = b1_1;
        if (loaded < T) {
            a0_1 = *(const uint4*)AgN; a1_1 = *(const uint4*)(AgN + 8);
            b0_1 = *(const uint4*)BgN; b1_1 = *(const uint4*)(BgN + 8);
            AgN += 64; BgN += 64; ++loaded;
        }
        __syncthreads();
        #pragma unroll
        for (int s = 0; s < 2; ++s) {
            bf16x8 af0 = *(const bf16x8*)&As[1][wm * 32 + fr][s * 32 + fk];
            bf16x8 af1 = *(const bf16x8*)&As[1][wm * 32 + 16 + fr][s * 32 + fk];
            bf16x8 bf0 = *(const bf16x8*)&Bs[1][wn * 32 + fr][s * 32 + fk];
            bf16x8 bf1 = *(const bf16x8*)&Bs[1][wn * 32 + 16 + fr][s * 32 + fk];
            acc[0][0] = __builtin_amdgcn_mfma_f32_16x16x32_bf16(af0, bf0, acc[0][0], 0, 0, 0);
            acc[0][1] = __builtin_amdgcn_mfma_f32_16x16x32_bf16(af0, bf1, acc[0][1], 0, 0, 0);
            acc[1][0] = __builtin_amdgcn_mfma_f32_16x16x32_bf16(af1, bf0, acc[1][0], 0, 0, 0);
            acc[1][1] = __builtin_amdgcn_mfma_f32_16x16x32_bf16(af1, bf1, acc[1][1], 0, 0, 0);
        }
    }
    const int cr   = (lane >> 4) << 2;
    const int ccol = lane & 15;
    #pragma unroll
    for (int i = 0; i < 2; ++i)
        #pragma unroll
        for (int j = 0; j < 2; ++j) {
            int col = bn + wn * 32 + j * 16 + ccol;
            float bsv = biasb[col];
            #pragma unroll
            for (int r = 0; r < 4; ++r) {
                int row = bm + wm * 32 + i * 16 + cr + r;
                float v = acc[i][j][r] + bsv;
                if (RESID) v += Rp[(size_t)row * N + col];
                if (RELU)  v = fmaxf(v, 0.f);
                if (OUT_BF16) ((unsigned short*)Cout + z * cZ)[(size_t)row * N + col] = f2b(v);
                else          ((float*)Cout)[(size_t)row * N + col] = v;
            }
        }
}

// ============ shared attention phase =========================================
template<int CAUSAL>
__device__ __forceinline__ void attn_phase(
        const unsigned short* Ks, const unsigned short* Vt,
        const unsigned short* Qs, unsigned short* Ps,
        int qbase, int brow, int hoff, unsigned short* __restrict__ Op,
        int lane, int wid)
{
    const int fr = lane & 15, fg = lane >> 4;
    f32x4 accs[8];
    #pragma unroll
    for (int kf = 0; kf < 8; ++kf) accs[kf] = (f32x4){0.f, 0.f, 0.f, 0.f};
    bf16x8 aq0 = *(const bf16x8*)&Qs[(wid * 16 + fr) * 72 + fg * 8];
    bf16x8 aq1 = *(const bf16x8*)&Qs[(wid * 16 + fr) * 72 + 32 + fg * 8];
    #pragma unroll
    for (int kf = 0; kf < 8; ++kf) {
        bf16x8 bk0 = *(const bf16x8*)&Ks[(kf * 16 + fr) * 72 + fg * 8];
        bf16x8 bk1 = *(const bf16x8*)&Ks[(kf * 16 + fr) * 72 + 32 + fg * 8];
        accs[kf] = __builtin_amdgcn_mfma_f32_16x16x32_bf16(aq0, bk0, accs[kf], 0, 0, 0);
        accs[kf] = __builtin_amdgcn_mfma_f32_16x16x32_bf16(aq1, bk1, accs[kf], 0, 0, 0);
    }
    const float SC = 0.125f * 1.44269504f;
    float linv[4];
    #pragma unroll
    for (int r = 0; r < 4; ++r) {
        int qrow = qbase + wid * 16 + fg * 4 + r;
        float sv[8];
        #pragma unroll
        for (int kf = 0; kf < 8; ++kf) {
            float s = accs[kf][r] * SC;
            if (CAUSAL) {
                int key = kf * 16 + fr;
                if (key > qrow) s = -1e30f;
            }
            sv[kf] = s;
        }
        float m = sv[0];
        #pragma unroll
        for (int kf = 1; kf < 8; ++kf) m = fmaxf(m, sv[kf]);
        #pragma unroll
        for (int o = 1; o < 16; o <<= 1) m = fmaxf(m, __shfl_xor(m, o));
        float l = 0.f;
        #pragma unroll
        for (int kf = 0; kf < 8; ++kf) {
            float p = exp2f(sv[kf] - m);
            l += p;
            Ps[(wid * 16 + fg * 4 + r) * 136 + kf * 16 + fr] = f2b(p);
        }
        #pragma unroll
        for (int o = 1; o < 16; o <<= 1) l += __shfl_xor(l, o);
        linv[r] = 1.f / l;
    }
    f32x4 acco[4];
    #pragma unroll
    for (int df = 0; df < 4; ++df) acco[df] = (f32x4){0.f, 0.f, 0.f, 0.f};
    #pragma unroll
    for (int ks = 0; ks < 4; ++ks) {
        bf16x8 pa = *(const bf16x8*)&Ps[(wid * 16 + fr) * 136 + ks * 32 + fg * 8];
        #pragma unroll
        for (int df = 0; df < 4; ++df) {
            bf16x8 vb = *(const bf16x8*)&Vt[(df * 16 + fr) * 136 + ks * 32 + fg * 8];
            acco[df] = __builtin_amdgcn_mfma_f32_16x16x32_bf16(pa, vb, acco[df], 0, 0, 0);
        }
    }
    #pragma unroll
    for (int df = 0; df < 4; ++df)
        #pragma unroll
        for (int r = 0; r < 4; ++r) {
            int qrow = qbase + wid * 16 + fg * 4 + r;
            Op[(size_t)(brow + qrow) * D + hoff + df * 16 + fr] = f2b(acco[df][r] * linv[r]);
        }
}

// ---------------- standalone attention (proven) -----------------------------
template<int CAUSAL>
__global__ __launch_bounds__(256) void attn_kernel(
        const unsigned short* __restrict__ Qp, int qs,
        const unsigned short* __restrict__ Kp,
        const unsigned short* __restrict__ Vp, int kvs,
        unsigned short* __restrict__ Op)
{
    __shared__ unsigned short Ks[128 * 72];
    __shared__ unsigned short Qs[64 * 72];
    __shared__ unsigned short Vt[64 * 136];
    __shared__ unsigned short Ps[64 * 136];
    const int bh    = blockIdx.x >> 1;
    const int qbase = (blockIdx.x & 1) << 6;
    const int brow  = (bh >> 3) * SEQ;
    const int hoff  = (bh & 7) * DHEAD;
    const int tid = threadIdx.x, lane = tid & 63, wid = tid >> 6;

    #pragma unroll
    for (int it = 0; it < 4; ++it) {
        int idx = it * 256 + tid;
        int row = idx >> 3;
        int c8  = (idx & 7) << 3;
        *(uint4*)&Ks[row * 72 + c8] =
            *(const uint4*)(Kp + (size_t)(brow + row) * kvs + hoff + c8);
        uint4 vu = *(const uint4*)(Vp + (size_t)(brow + row) * kvs + hoff + c8);
        unsigned arr[4] = {vu.x, vu.y, vu.z, vu.w};
        #pragma unroll
        for (int j = 0; j < 8; ++j)
            Vt[(c8 + j) * 136 + row] = (unsigned short)(arr[j >> 1] >> ((j & 1) * 16));
    }
    #pragma unroll
    for (int it = 0; it < 2; ++it) {
        int idx = it * 256 + tid;
        int row = idx >> 3;
        int c8  = (idx & 7) << 3;
        *(uint4*)&Qs[row * 72 + c8] =
            *(const uint4*)(Qp + (size_t)(brow + qbase + row) * qs + hoff + c8);
    }
    __syncthreads();
    attn_phase<CAUSAL>(Ks, Vt, Qs, Ps, qbase, brow, hoff, Op, lane, wid);
}

// ---------------- fused Q-proj + cross-attention ----------------------------
__global__ __launch_bounds__(256) void xattn_kernel(
        const unsigned short* __restrict__ Hb,   // [1024][512] dec LN'd
        const unsigned short* __restrict__ Wq,   // [512][512] q^T (first block)
        const float* __restrict__ bias,          // [1536] (q at offset 0)
        const unsigned short* __restrict__ KV,   // [1024][1024]
        unsigned short* __restrict__ Op)
{
    __shared__ __align__(16) char lds[63488];
    unsigned short* Ks  = (unsigned short*)(lds);
    unsigned short* Vt  = (unsigned short*)(lds + 18432);
    unsigned short* Qs  = (unsigned short*)(lds + 35840);
    unsigned short* Ps  = (unsigned short*)(lds + 46080);
    unsigned short* Hs  = (unsigned short*)(lds + 35840);
    unsigned short* Wqs = (unsigned short*)(lds + 46080);

    const int bh = blockIdx.x >> 1;
    const int qbase = (blockIdx.x & 1) << 6;
    const int h = bh & 7;
    const int brow = (bh >> 3) * SEQ;
    const int hoff = h * DHEAD;
    const int tid = threadIdx.x, lane = tid & 63, wid = tid >> 6;
    const int fr = lane & 15, fg = lane >> 4;

    #pragma unroll
    for (int it = 0; it < 4; ++it) {
        int idx = it * 256 + tid;
        int row = idx >> 3, c8 = (idx & 7) << 3;
        const unsigned short* kvrow = KV + (size_t)(brow + row) * 1024 + hoff;
        *(uint4*)&Ks[row * 72 + c8] = *(const uint4*)(kvrow + c8);
        uint4 vu = *(const uint4*)(kvrow + 512 + c8);
        unsigned arr[4] = {vu.x, vu.y, vu.z, vu.w};
        #pragma unroll
        for (int j = 0; j < 8; ++j)
            Vt[(c8 + j) * 136 + row] = (unsigned short)(arr[j >> 1] >> ((j & 1) * 16));
    }
    f32x4 accQ[4];
    #pragma unroll
    for (int n = 0; n < 4; ++n) accQ[n] = (f32x4){0.f, 0.f, 0.f, 0.f};
    for (int kt = 0; kt < 8; ++kt) {
        #pragma unroll
        for (int it = 0; it < 2; ++it) {
            int idx = it * 256 + tid;
            int row = idx >> 3, c8 = (idx & 7) << 3;
            *(uint4*)&Hs[row * 72 + c8] =
                *(const uint4*)(Hb + (size_t)(brow + qbase + row) * 512 + kt * 64 + c8);
            *(uint4*)&Wqs[row * 72 + c8] =
                *(const uint4*)(Wq + (size_t)(hoff + row) * 512 + kt * 64 + c8);
        }
        __syncthreads();
        #pragma unroll
        for (int s = 0; s < 2; ++s) {
            int fk = s * 32 + fg * 8;
            bf16x8 hq = *(const bf16x8*)&Hs[(wid * 16 + fr) * 72 + fk];
            #pragma unroll
            for (int n = 0; n < 4; ++n) {
                bf16x8 wq = *(const bf16x8*)&Wqs[(n * 16 + fr) * 72 + fk];
                accQ[n] = __builtin_amdgcn_mfma_f32_16x16x32_bf16(hq, wq, accQ[n], 0, 0, 0);
            }
        }
        __syncthreads();
    }
    #pragma unroll
    for (int n = 0; n < 4; ++n) {
        int d = n * 16 + fr;
        float bq = bias[hoff + d];
        #pragma unroll
        for (int r = 0; r < 4; ++r) {
            int ql = wid * 16 + fg * 4 + r;
            Qs[ql * 72 + d] = f2b(accQ[n][r] + bq);
        }
    }
    __syncthreads();
    attn_phase<0>(Ks, Vt, Qs, Ps, qbase, brow, hoff, Op, lane, wid);
}

// ---------------------------------------------------------------------------
extern "C" void kernel_launch(void* const* d_in, const int* in_sizes, int n_in,
                              void* d_out, int out_size, void* d_ws, size_t ws_size,
                              hipStream_t stream)
{
    const int*   src       = (const int*)d_in[0];
    const int*   tgt       = (const int*)d_in[1];
    const float* src_emb   = (const float*)d_in[2];
    const float* tgt_emb   = (const float*)d_in[3];
    const float* enc_qkv_w = (const float*)d_in[4];
    const float* enc_qkv_b = (const float*)d_in[5];
    const float* enc_o_w   = (const float*)d_in[6];
    const float* enc_o_b   = (const float*)d_in[7];
    const float* enc_ff_w1 = (const float*)d_in[8];
    const float* enc_ff_b1 = (const float*)d_in[9];
    const float* enc_ff_w2 = (const float*)d_in[10];
    const float* enc_ff_b2 = (const float*)d_in[11];
    const float* enc_ln_g  = (const float*)d_in[12];
    const float* enc_ln_b  = (const float*)d_in[13];
    const float* enc_fg    = (const float*)d_in[14];
    const float* enc_fb    = (const float*)d_in[15];
    const float* dec_sqkv_w = (const float*)d_in[16];
    const float* dec_sqkv_b = (const float*)d_in[17];
    const float* dec_so_w   = (const float*)d_in[18];
    const float* dec_so_b   = (const float*)d_in[19];
    const float* dec_cqkv_w = (const float*)d_in[20];
    const float* dec_cqkv_b = (const float*)d_in[21];
    const float* dec_co_w   = (const float*)d_in[22];
    const float* dec_co_b   = (const float*)d_in[23];
    const float* dec_ff_w1  = (const float*)d_in[24];
    const float* dec_ff_b1  = (const float*)d_in[25];
    const float* dec_ff_w2  = (const float*)d_in[26];
    const float* dec_ff_b2  = (const float*)d_in[27];
    const float* dec_ln_g   = (const float*)d_in[28];
    const float* dec_ln_b   = (const float*)d_in[29];
    const float* dec_fg     = (const float*)d_in[30];
    const float* dec_fb     = (const float*)d_in[31];

    // ---- workspace carve ----
    unsigned short* wp = (unsigned short*)d_ws;
    unsigned short* WencQKV  = wp; wp += (size_t)6 * 786432;
    unsigned short* WencO    = wp; wp += (size_t)6 * 262144;
    unsigned short* WencF1   = wp; wp += (size_t)6 * 1048576;
    unsigned short* WencF2   = wp; wp += (size_t)6 * 1048576;
    unsigned short* WdecSQKV = wp; wp += (size_t)6 * 786432;
    unsigned short* WdecSO   = wp; wp += (size_t)6 * 262144;
    unsigned short* WdecCQKV = wp; wp += (size_t)6 * 786432;
    unsigned short* WdecCO   = wp; wp += (size_t)6 * 262144;
    unsigned short* WdecF1   = wp; wp += (size_t)6 * 1048576;
    unsigned short* WdecF2   = wp; wp += (size_t)6 * 1048576;
    unsigned short* Hb   = wp; wp += ROWS * D;
    unsigned short* QKVb = wp; wp += ROWS * 3 * D;
    unsigned short* CKVall = wp; wp += (size_t)6 * ROWS * 1024;
    unsigned short* ATTb = wp; wp += ROWS * D;
    unsigned short* F1b  = wp; wp += ROWS * DFF;
    unsigned short* MEMb = wp; wp += ROWS * D;
    float* X  = (float*)wp;  wp += ROWS * D * 2;   // fp32 encoder residual
    float* X2 = (float*)wp;  wp += ROWS * D * 2;   // fp32 decoder residual

    // ---- batched weight transposes: 3 launches (ALL 6 square groups) ----
    {
        TMulti mA = {{ {enc_qkv_w,  WencQKV,  18},
                       {enc_o_w,    WencO,     6},
                       {dec_sqkv_w, WdecSQKV, 18},
                       {dec_so_w,   WdecSO,    6},
                       {dec_cqkv_w, WdecCQKV, 18},
                       {dec_co_w,   WdecCO,    6} }};
        transpose_multi_kernel<<<dim3(16, 16, 72), 256, 0, stream>>>(mA, 512, 512);
        TMulti mB = {{ {enc_ff_w1, WencF1, 6},
                       {dec_ff_w1, WdecF1, 6},
                       {nullptr, nullptr, 1 << 30}, {nullptr, nullptr, 1 << 30},
                       {nullptr, nullptr, 1 << 30}, {nullptr, nullptr, 1 << 30} }};
        transpose_multi_kernel<<<dim3(64, 16, 12), 256, 0, stream>>>(mB, 512, 2048);
        TMulti mC = {{ {enc_ff_w2, WencF2, 6},
                       {dec_ff_w2, WdecF2, 6},
                       {nullptr, nullptr, 1 << 30}, {nullptr, nullptr, 1 << 30},
                       {nullptr, nullptr, 1 << 30}, {nullptr, nullptr, 1 << 30} }};
        transpose_multi_kernel<<<dim3(16, 64, 12), 256, 0, stream>>>(mC, 2048, 512);
    }

    // ---- both embeddings upfront (z=2) ----
    embed_pe_kernel<<<dim3(2048, 1, 2), 256, 0, stream>>>(src, tgt, src_emb, tgt_emb, X, X2);

    // ---------------- encoder ----------------
    for (int i = 0; i < LAYERS; ++i) {
        ln_kernel<1><<<256, 256, 0, stream>>>(X, enc_ln_g + (size_t)(i*2+0)*D, enc_ln_b + (size_t)(i*2+0)*D, Hb);
        mgemm_kernel<0,0,1><<<dim3(24,16,1), 256, 0, stream>>>(Hb, WencQKV + (size_t)i*786432,
                enc_qkv_b + (size_t)i*1536, nullptr, QKVb, 1536, 512, 0, 0, 0, 0);
        attn_kernel<0><<<128, 256, 0, stream>>>(QKVb, 1536, QKVb + 512, QKVb + 1024, 1536, ATTb);
        mgemm_kernel<1,0,0><<<dim3(8,16,1), 256, 0, stream>>>(ATTb, WencO + (size_t)i*262144,
                enc_o_b + (size_t)i*512, X, X, 512, 512, 0, 0, 0, 0);
        ln_kernel<1><<<256, 256, 0, stream>>>(X, enc_ln_g + (size_t)(i*2+1)*D, enc_ln_b + (size_t)(i*2+1)*D, Hb);
        mgemm_kernel<0,1,1><<<dim3(32,16,1), 256, 0, stream>>>(Hb, WencF1 + (size_t)i*1048576,
                enc_ff_b1 + (size_t)i*DFF, nullptr, F1b, DFF, 512, 0, 0, 0, 0);
        mgemm_kernel<1,0,0><<<dim3(8,16,1), 256, 0, stream>>>(F1b, WencF2 + (size_t)i*1048576,
                enc_ff_b2 + (size_t)i*512, X, X, 512, DFF, 0, 0, 0, 0);
    }
    ln_kernel<1><<<256, 256, 0, stream>>>(X, enc_fg, enc_fb, MEMb);

    // ---- all 6 decoder layers' cross K/V: one batched GEMM ----
    mgemm_kernel<0,0,1><<<dim3(16,16,6), 256, 0, stream>>>(MEMb, WdecCQKV + 262144,
            dec_cqkv_b + 512, nullptr, CKVall, 1024, 512,
            0, 786432, 1536, (long)ROWS * 1024);

    // ---------------- decoder ----------------
    for (int i = 0; i < LAYERS; ++i) {
        ln_kernel<1><<<256, 256, 0, stream>>>(X2, dec_ln_g + (size_t)(i*3+0)*D, dec_ln_b + (size_t)(i*3+0)*D, Hb);
        mgemm_kernel<0,0,1><<<dim3(24,16,1), 256, 0, stream>>>(Hb, WdecSQKV + (size_t)i*786432,
                dec_sqkv_b + (size_t)i*1536, nullptr, QKVb, 1536, 512, 0, 0, 0, 0);
        attn_kernel<1><<<128, 256, 0, stream>>>(QKVb, 1536, QKVb + 512, QKVb + 1024, 1536, ATTb);
        mgemm_kernel<1,0,0><<<dim3(8,16,1), 256, 0, stream>>>(ATTb, WdecSO + (size_t)i*262144,
                dec_so_b + (size_t)i*512, X2, X2, 512, 512, 0, 0, 0, 0);
        ln_kernel<1><<<256, 256, 0, stream>>>(X2, dec_ln_g + (size_t)(i*3+1)*D, dec_ln_b + (size_t)(i*3+1)*D, Hb);
        xattn_kernel<<<128, 256, 0, stream>>>(Hb, WdecCQKV + (size_t)i*786432,
                dec_cqkv_b + (size_t)i*1536, CKVall + (size_t)i*ROWS*1024, ATTb);
        mgemm_kernel<1,0,0><<<dim3(8,16,1), 256, 0, stream>>>(ATTb, WdecCO + (size_t)i*262144,
                dec_co_b + (size_t)i*512, X2, X2, 512, 512, 0, 0, 0, 0);
        ln_kernel<1><<<256, 256, 0, stream>>>(X2, dec_ln_g + (size_t)(i*3+2)*D, dec_ln_b + (size_t)(i*3+2)*D, Hb);
        mgemm_kernel<0,1,1><<<dim3(32,16,1), 256, 0, stream>>>(Hb, WdecF1 + (size_t)i*1048576,
                dec_ff_b1 + (size_t)i*DFF, nullptr, F1b, DFF, 512, 0, 0, 0, 0);
        mgemm_kernel<1,0,0><<<dim3(8,16,1), 256, 0, stream>>>(F1b, WdecF2 + (size_t)i*1048576,
                dec_ff_b2 + (size_t)i*512, X2, X2, 512, DFF, 0, 0, 0, 0);
    }
    ln_kernel<0><<<256, 256, 0, stream>>>(X2, dec_fg, dec_fb, d_out);
}

// Round 18
// 715.940 us; speedup vs baseline: 1.0604x; 1.0155x over previous
//
#include <hip/hip_runtime.h>
#include <hip/hip_bf16.h>
#include <math.h>

#define D 512
#define NH 8
#define DHEAD 64
#define LAYERS 6
#define DFF 2048
#define BATCH 8
#define SEQ 128
#define ROWS (BATCH * SEQ)   // 1024

typedef float f32x4 __attribute__((ext_vector_type(4)));
typedef short bf16x8 __attribute__((ext_vector_type(8)));

__device__ __forceinline__ unsigned short f2b(float x) {
    return __builtin_bit_cast(unsigned short, __float2bfloat16(x));
}

// ---------------- embedding + positional encoding (both streams, z=2) -------
__global__ __launch_bounds__(256) void embed_pe_kernel(
        const int* __restrict__ tok0, const int* __restrict__ tok1,
        const float* __restrict__ emb0, const float* __restrict__ emb1,
        float* __restrict__ out0, float* __restrict__ out1)
{
    const int z = blockIdx.z;
    const int* tok = z ? tok1 : tok0;
    const float* emb = z ? emb1 : emb0;
    float* out = z ? out1 : out0;
    int i = blockIdx.x * 256 + threadIdx.x;
    int bs = i >> 9;
    int d  = i & 511;
    int s  = bs & (SEQ - 1);
    int tk = tok[bs];
    float dv  = expf(-(float)(d & ~1) * (9.210340371976184f / 512.0f));
    float arg = (float)s * dv;
    float pe  = (d & 1) ? cosf(arg) : sinf(arg);
    out[i] = emb[(size_t)tk * D + d] * 22.627416997969522f + pe;
}

// ---------------- batched multi-source transpose + fp32->bf16 ---------------
struct TSeg { const float* src; unsigned short* dst; int cnt; };
struct TMulti { TSeg seg[6]; };

__global__ __launch_bounds__(256) void transpose_multi_kernel(TMulti m, int R, int C)
{
    __shared__ float t[32][33];
    int z = blockIdx.z, s = 0;
    while (z >= m.seg[s].cnt) { z -= m.seg[s].cnt; ++s; }
    const float* src = m.seg[s].src + (size_t)z * R * C;
    unsigned short* dst = m.seg[s].dst + (size_t)z * R * C;
    const int r0 = blockIdx.y << 5, c0 = blockIdx.x << 5;
    const int tid = threadIdx.x;
    const int rr = tid >> 3, cc = (tid & 7) << 2;
    float4 v = *(const float4*)(src + (size_t)(r0 + rr) * C + c0 + cc);
    t[rr][cc] = v.x; t[rr][cc + 1] = v.y; t[rr][cc + 2] = v.z; t[rr][cc + 3] = v.w;
    __syncthreads();
    const int oc = tid >> 3, or4 = (tid & 7) << 2;
    ushort4 o;
    o.x = f2b(t[or4 + 0][oc]);
    o.y = f2b(t[or4 + 1][oc]);
    o.z = f2b(t[or4 + 2][oc]);
    o.w = f2b(t[or4 + 3][oc]);
    *(ushort4*)(dst + (size_t)(c0 + oc) * R + r0 + or4) = o;
}

// ---------------- LayerNorm: one wave per row of 512 ------------------------
template<int OUT_BF16>
__global__ __launch_bounds__(256) void ln_kernel(const float* __restrict__ x,
        const float* __restrict__ g, const float* __restrict__ bta,
        void* __restrict__ outp)
{
    int lane = threadIdx.x & 63;
    int row  = (blockIdx.x << 2) + (threadIdx.x >> 6);
    const float* xr = x + (size_t)row * D;
    int c = lane * 8;
    float4 v0 = *(const float4*)(xr + c);
    float4 v1 = *(const float4*)(xr + c + 4);
    float s  = v0.x + v0.y + v0.z + v0.w + v1.x + v1.y + v1.z + v1.w;
    float sq = v0.x*v0.x + v0.y*v0.y + v0.z*v0.z + v0.w*v0.w
             + v1.x*v1.x + v1.y*v1.y + v1.z*v1.z + v1.w*v1.w;
    #pragma unroll
    for (int o = 32; o; o >>= 1) {
        s  += __shfl_xor(s, o);
        sq += __shfl_xor(sq, o);
    }
    float mean = s * (1.0f / D);
    float var  = sq * (1.0f / D) - mean * mean;
    float inv  = rsqrtf(var + 1e-6f);
    float4 g0 = *(const float4*)(g + c),   g1 = *(const float4*)(g + c + 4);
    float4 b0 = *(const float4*)(bta + c), b1 = *(const float4*)(bta + c + 4);
    float4 o0, o1;
    o0.x = g0.x * (v0.x - mean) * inv + b0.x;
    o0.y = g0.y * (v0.y - mean) * inv + b0.y;
    o0.z = g0.z * (v0.z - mean) * inv + b0.z;
    o0.w = g0.w * (v0.w - mean) * inv + b0.w;
    o1.x = g1.x * (v1.x - mean) * inv + b1.x;
    o1.y = g1.y * (v1.y - mean) * inv + b1.y;
    o1.z = g1.z * (v1.z - mean) * inv + b1.z;
    o1.w = g1.w * (v1.w - mean) * inv + b1.w;
    if (OUT_BF16) {
        unsigned short* orow = (unsigned short*)outp + (size_t)row * D + c;
        uint4 o;
        o.x = (unsigned int)f2b(o0.x) | ((unsigned int)f2b(o0.y) << 16);
        o.y = (unsigned int)f2b(o0.z) | ((unsigned int)f2b(o0.w) << 16);
        o.z = (unsigned int)f2b(o1.x) | ((unsigned int)f2b(o1.y) << 16);
        o.w = (unsigned int)f2b(o1.z) | ((unsigned int)f2b(o1.w) << 16);
        *(uint4*)orow = o;
    } else {
        float* orow = (float*)outp + (size_t)row * D + c;
        *(float4*)(orow)     = o0;
        *(float4*)(orow + 4) = o1;
    }
}

// ---------------- bf16 MFMA GEMM (dbuf, BK=64, depth-2 prefetch, z-batch) ---
template<int RESID, int RELU, int OUT_BF16>
__global__ __launch_bounds__(256) void mgemm_kernel(
        const unsigned short* __restrict__ A,
        const unsigned short* __restrict__ Wt,
        const float* __restrict__ bias,
        const float* __restrict__ Rp,
        void* __restrict__ Cout,
        int N, int K,
        long aZ, long wZ, long bZ, long cZ)
{
    __shared__ unsigned short As[2][64][72];
    __shared__ unsigned short Bs[2][64][72];
    const long z = blockIdx.z;
    const unsigned short* Ab = A  + z * aZ;
    const unsigned short* Wb = Wt + z * wZ;
    const float* biasb = bias + z * bZ;
    const int tid  = threadIdx.x;
    const int lane = tid & 63, wid = tid >> 6;
    const int wm = wid >> 1, wn = wid & 1;
    const int bm = blockIdx.y << 6, bn = blockIdx.x << 6;
    const int srow = tid >> 2, sk = (tid & 3) << 4;
    const unsigned short* Ag = Ab + (size_t)(bm + srow) * K + sk;
    const unsigned short* Bg = Wb + (size_t)(bn + srow) * K + sk;
    const int fr = lane & 15;
    const int fk = (lane >> 4) << 3;
    f32x4 acc[2][2];
    #pragma unroll
    for (int i = 0; i < 2; ++i)
        #pragma unroll
        for (int j = 0; j < 2; ++j)
            acc[i][j] = (f32x4){0.f, 0.f, 0.f, 0.f};

    const int T = K >> 6;   // always even (8 or 32), >= 2
    uint4 a0_0 = *(const uint4*)Ag,        a1_0 = *(const uint4*)(Ag + 8);
    uint4 b0_0 = *(const uint4*)Bg,        b1_0 = *(const uint4*)(Bg + 8);
    uint4 a0_1 = *(const uint4*)(Ag + 64), a1_1 = *(const uint4*)(Ag + 72);
    uint4 b0_1 = *(const uint4*)(Bg + 64), b1_1 = *(const uint4*)(Bg + 72);
    const unsigned short* AgN = Ag + 128;
    const unsigned short* BgN = Bg + 128;
    int loaded = 2;

    for (int t = 0; t < T; t += 2) {
        *(uint4*)&As[0][srow][sk]     = a0_0;
        *(uint4*)&As[0][srow][sk + 8] = a1_0;
        *(uint4*)&Bs[0][srow][sk]     = b0_0;
        *(uint4*)&Bs[0][srow][sk + 8] = b1_0;
        if (loaded < T) {
            a0_0 = *(const uint4*)AgN; a1_0 = *(const uint4*)(AgN + 8);
            b0_0 = *(const uint4*)BgN; b1_0 = *(const uint4*)(BgN + 8);
            AgN += 64; BgN += 64; ++loaded;
        }
        __syncthreads();
        #pragma unroll
        for (int s = 0; s < 2; ++s) {
            bf16x8 af0 = *(const bf16x8*)&As[0][wm * 32 + fr][s * 32 + fk];
            bf16x8 af1 = *(const bf16x8*)&As[0][wm * 32 + 16 + fr][s * 32 + fk];
            bf16x8 bf0 = *(const bf16x8*)&Bs[0][wn * 32 + fr][s * 32 + fk];
            bf16x8 bf1 = *(const bf16x8*)&Bs[0][wn * 32 + 16 + fr][s * 32 + fk];
            acc[0][0] = __builtin_amdgcn_mfma_f32_16x16x32_bf16(af0, bf0, acc[0][0], 0, 0, 0);
            acc[0][1] = __builtin_amdgcn_mfma_f32_16x16x32_bf16(af0, bf1, acc[0][1], 0, 0, 0);
            acc[1][0] = __builtin_amdgcn_mfma_f32_16x16x32_bf16(af1, bf0, acc[1][0], 0, 0, 0);
            acc[1][1] = __builtin_amdgcn_mfma_f32_16x16x32_bf16(af1, bf1, acc[1][1], 0, 0, 0);
        }
        *(uint4*)&As[1][srow][sk]     = a0_1;
        *(uint4*)&As[1][srow][sk + 8] = a1_1;
        *(uint4*)&Bs[1][srow][sk]     = b0_1;
        *(uint4*)&Bs[1][srow][sk + 8] = b1_1;
        if (loaded < T) {
            a0_1 = *(const uint4*)AgN; a1_1 = *(const uint4*)(AgN + 8);
            b0_1 = *(const uint4*)BgN; b1_1 = *(const uint4*)(BgN + 8);
            AgN += 64; BgN += 64; ++loaded;
        }
        __syncthreads();
        #pragma unroll
        for (int s = 0; s < 2; ++s) {
            bf16x8 af0 = *(const bf16x8*)&As[1][wm * 32 + fr][s * 32 + fk];
            bf16x8 af1 = *(const bf16x8*)&As[1][wm * 32 + 16 + fr][s * 32 + fk];
            bf16x8 bf0 = *(const bf16x8*)&Bs[1][wn * 32 + fr][s * 32 + fk];
            bf16x8 bf1 = *(const bf16x8*)&Bs[1][wn * 32 + 16 + fr][s * 32 + fk];
            acc[0][0] = __builtin_amdgcn_mfma_f32_16x16x32_bf16(af0, bf0, acc[0][0], 0, 0, 0);
            acc[0][1] = __builtin_amdgcn_mfma_f32_16x16x32_bf16(af0, bf1, acc[0][1], 0, 0, 0);
            acc[1][0] = __builtin_amdgcn_mfma_f32_16x16x32_bf16(af1, bf0, acc[1][0], 0, 0, 0);
            acc[1][1] = __builtin_amdgcn_mfma_f32_16x16x32_bf16(af1, bf1, acc[1][1], 0, 0, 0);
        }
    }
    const int cr   = (lane >> 4) << 2;
    const int ccol = lane & 15;
    #pragma unroll
    for (int i = 0; i < 2; ++i)
        #pragma unroll
        for (int j = 0; j < 2; ++j) {
            int col = bn + wn * 32 + j * 16 + ccol;
            float bsv = biasb[col];
            #pragma unroll
            for (int r = 0; r < 4; ++r) {
                int row = bm + wm * 32 + i * 16 + cr + r;
                float v = acc[i][j][r] + bsv;
                if (RESID) v += Rp[(size_t)row * N + col];
                if (RELU)  v = fmaxf(v, 0.f);
                if (OUT_BF16) ((unsigned short*)Cout + z * cZ)[(size_t)row * N + col] = f2b(v);
                else          ((float*)Cout)[(size_t)row * N + col] = v;
            }
        }
}

// ============ shared attention phase =========================================
template<int CAUSAL>
__device__ __forceinline__ void attn_phase(
        const unsigned short* Ks, const unsigned short* Vt,
        const unsigned short* Qs, unsigned short* Ps,
        int qbase, int brow, int hoff, unsigned short* __restrict__ Op,
        int lane, int wid)
{
    const int fr = lane & 15, fg = lane >> 4;
    f32x4 accs[8];
    #pragma unroll
    for (int kf = 0; kf < 8; ++kf) accs[kf] = (f32x4){0.f, 0.f, 0.f, 0.f};
    bf16x8 aq0 = *(const bf16x8*)&Qs[(wid * 16 + fr) * 72 + fg * 8];
    bf16x8 aq1 = *(const bf16x8*)&Qs[(wid * 16 + fr) * 72 + 32 + fg * 8];
    #pragma unroll
    for (int kf = 0; kf < 8; ++kf) {
        bf16x8 bk0 = *(const bf16x8*)&Ks[(kf * 16 + fr) * 72 + fg * 8];
        bf16x8 bk1 = *(const bf16x8*)&Ks[(kf * 16 + fr) * 72 + 32 + fg * 8];
        accs[kf] = __builtin_amdgcn_mfma_f32_16x16x32_bf16(aq0, bk0, accs[kf], 0, 0, 0);
        accs[kf] = __builtin_amdgcn_mfma_f32_16x16x32_bf16(aq1, bk1, accs[kf], 0, 0, 0);
    }
    const float SC = 0.125f * 1.44269504f;
    float linv[4];
    #pragma unroll
    for (int r = 0; r < 4; ++r) {
        int qrow = qbase + wid * 16 + fg * 4 + r;
        float sv[8];
        #pragma unroll
        for (int kf = 0; kf < 8; ++kf) {
            float s = accs[kf][r] * SC;
            if (CAUSAL) {
                int key = kf * 16 + fr;
                if (key > qrow) s = -1e30f;
            }
            sv[kf] = s;
        }
        float m = sv[0];
        #pragma unroll
        for (int kf = 1; kf < 8; ++kf) m = fmaxf(m, sv[kf]);
        #pragma unroll
        for (int o = 1; o < 16; o <<= 1) m = fmaxf(m, __shfl_xor(m, o));
        float l = 0.f;
        #pragma unroll
        for (int kf = 0; kf < 8; ++kf) {
            float p = exp2f(sv[kf] - m);
            l += p;
            Ps[(wid * 16 + fg * 4 + r) * 136 + kf * 16 + fr] = f2b(p);
        }
        #pragma unroll
        for (int o = 1; o < 16; o <<= 1) l += __shfl_xor(l, o);
        linv[r] = 1.f / l;
    }
    f32x4 acco[4];
    #pragma unroll
    for (int df = 0; df < 4; ++df) acco[df] = (f32x4){0.f, 0.f, 0.f, 0.f};
    #pragma unroll
    for (int ks = 0; ks < 4; ++ks) {
        bf16x8 pa = *(const bf16x8*)&Ps[(wid * 16 + fr) * 136 + ks * 32 + fg * 8];
        #pragma unroll
        for (int df = 0; df < 4; ++df) {
            bf16x8 vb = *(const bf16x8*)&Vt[(df * 16 + fr) * 136 + ks * 32 + fg * 8];
            acco[df] = __builtin_amdgcn_mfma_f32_16x16x32_bf16(pa, vb, acco[df], 0, 0, 0);
        }
    }
    #pragma unroll
    for (int df = 0; df < 4; ++df)
        #pragma unroll
        for (int r = 0; r < 4; ++r) {
            int qrow = qbase + wid * 16 + fg * 4 + r;
            Op[(size_t)(brow + qrow) * D + hoff + df * 16 + fr] = f2b(acco[df][r] * linv[r]);
        }
}

// ---------------- standalone attention (proven) -----------------------------
template<int CAUSAL>
__global__ __launch_bounds__(256) void attn_kernel(
        const unsigned short* __restrict__ Qp, int qs,
        const unsigned short* __restrict__ Kp,
        const unsigned short* __restrict__ Vp, int kvs,
        unsigned short* __restrict__ Op)
{
    __shared__ unsigned short Ks[128 * 72];
    __shared__ unsigned short Qs[64 * 72];
    __shared__ unsigned short Vt[64 * 136];
    __shared__ unsigned short Ps[64 * 136];
    const int bh    = blockIdx.x >> 1;
    const int qbase = (blockIdx.x & 1) << 6;
    const int brow  = (bh >> 3) * SEQ;
    const int hoff  = (bh & 7) * DHEAD;
    const int tid = threadIdx.x, lane = tid & 63, wid = tid >> 6;

    #pragma unroll
    for (int it = 0; it < 4; ++it) {
        int idx = it * 256 + tid;
        int row = idx >> 3;
        int c8  = (idx & 7) << 3;
        *(uint4*)&Ks[row * 72 + c8] =
            *(const uint4*)(Kp + (size_t)(brow + row) * kvs + hoff + c8);
        uint4 vu = *(const uint4*)(Vp + (size_t)(brow + row) * kvs + hoff + c8);
        unsigned arr[4] = {vu.x, vu.y, vu.z, vu.w};
        #pragma unroll
        for (int j = 0; j < 8; ++j)
            Vt[(c8 + j) * 136 + row] = (unsigned short)(arr[j >> 1] >> ((j & 1) * 16));
    }
    #pragma unroll
    for (int it = 0; it < 2; ++it) {
        int idx = it * 256 + tid;
        int row = idx >> 3;
        int c8  = (idx & 7) << 3;
        *(uint4*)&Qs[row * 72 + c8] =
            *(const uint4*)(Qp + (size_t)(brow + qbase + row) * qs + hoff + c8);
    }
    __syncthreads();
    attn_phase<CAUSAL>(Ks, Vt, Qs, Ps, qbase, brow, hoff, Op, lane, wid);
}

// ---------------- fused Q-proj + cross-attention (depth-2 prefetch) ---------
__global__ __launch_bounds__(256) void xattn_kernel(
        const unsigned short* __restrict__ Hb,   // [1024][512] dec LN'd
        const unsigned short* __restrict__ Wq,   // [512][512] q^T (first block)
        const float* __restrict__ bias,          // [1536] (q at offset 0)
        const unsigned short* __restrict__ KV,   // [1024][1024]
        unsigned short* __restrict__ Op)
{
    __shared__ __align__(16) char lds[63488];
    unsigned short* Ks  = (unsigned short*)(lds);
    unsigned short* Vt  = (unsigned short*)(lds + 18432);
    unsigned short* Qs  = (unsigned short*)(lds + 35840);
    unsigned short* Ps  = (unsigned short*)(lds + 46080);
    unsigned short* Hs  = (unsigned short*)(lds + 35840);
    unsigned short* Wqs = (unsigned short*)(lds + 46080);

    const int bh = blockIdx.x >> 1;
    const int qbase = (blockIdx.x & 1) << 6;
    const int h = bh & 7;
    const int brow = (bh >> 3) * SEQ;
    const int hoff = h * DHEAD;
    const int tid = threadIdx.x, lane = tid & 63, wid = tid >> 6;
    const int fr = lane & 15, fg = lane >> 4;

    #pragma unroll
    for (int it = 0; it < 4; ++it) {
        int idx = it * 256 + tid;
        int row = idx >> 3, c8 = (idx & 7) << 3;
        const unsigned short* kvrow = KV + (size_t)(brow + row) * 1024 + hoff;
        *(uint4*)&Ks[row * 72 + c8] = *(const uint4*)(kvrow + c8);
        uint4 vu = *(const uint4*)(kvrow + 512 + c8);
        unsigned arr[4] = {vu.x, vu.y, vu.z, vu.w};
        #pragma unroll
        for (int j = 0; j < 8; ++j)
            Vt[(c8 + j) * 136 + row] = (unsigned short)(arr[j >> 1] >> ((j & 1) * 16));
    }
    // ---- Q projection with depth-2 register prefetch ----
    const int rowA = tid >> 3, c8A = (tid & 7) << 3;
    const int rowB = rowA + 32;
    const unsigned short* HbB = Hb + (size_t)(brow + qbase) * 512 + c8A;
    const unsigned short* WqB = Wq + (size_t)hoff * 512 + c8A;
    f32x4 accQ[4];
    #pragma unroll
    for (int n = 0; n < 4; ++n) accQ[n] = (f32x4){0.f, 0.f, 0.f, 0.f};

    uint4 h0A = *(const uint4*)(HbB + (size_t)rowA * 512);
    uint4 h0B = *(const uint4*)(HbB + (size_t)rowB * 512);
    uint4 w0A = *(const uint4*)(WqB + (size_t)rowA * 512);
    uint4 w0B = *(const uint4*)(WqB + (size_t)rowB * 512);
    uint4 h1A = *(const uint4*)(HbB + (size_t)rowA * 512 + 64);
    uint4 h1B = *(const uint4*)(HbB + (size_t)rowB * 512 + 64);
    uint4 w1A = *(const uint4*)(WqB + (size_t)rowA * 512 + 64);
    uint4 w1B = *(const uint4*)(WqB + (size_t)rowB * 512 + 64);

    for (int kt = 0; kt < 8; kt += 2) {
        // even: stage set 0, reload for kt+2
        *(uint4*)&Hs[rowA * 72 + c8A]  = h0A;
        *(uint4*)&Hs[rowB * 72 + c8A]  = h0B;
        *(uint4*)&Wqs[rowA * 72 + c8A] = w0A;
        *(uint4*)&Wqs[rowB * 72 + c8A] = w0B;
        if (kt + 2 < 8) {
            int ko = (kt + 2) * 64;
            h0A = *(const uint4*)(HbB + (size_t)rowA * 512 + ko);
            h0B = *(const uint4*)(HbB + (size_t)rowB * 512 + ko);
            w0A = *(const uint4*)(WqB + (size_t)rowA * 512 + ko);
            w0B = *(const uint4*)(WqB + (size_t)rowB * 512 + ko);
        }
        __syncthreads();
        #pragma unroll
        for (int s = 0; s < 2; ++s) {
            int fk = s * 32 + fg * 8;
            bf16x8 hq = *(const bf16x8*)&Hs[(wid * 16 + fr) * 72 + fk];
            #pragma unroll
            for (int n = 0; n < 4; ++n) {
                bf16x8 wq = *(const bf16x8*)&Wqs[(n * 16 + fr) * 72 + fk];
                accQ[n] = __builtin_amdgcn_mfma_f32_16x16x32_bf16(hq, wq, accQ[n], 0, 0, 0);
            }
        }
        __syncthreads();
        // odd: stage set 1, reload for kt+3
        *(uint4*)&Hs[rowA * 72 + c8A]  = h1A;
        *(uint4*)&Hs[rowB * 72 + c8A]  = h1B;
        *(uint4*)&Wqs[rowA * 72 + c8A] = w1A;
        *(uint4*)&Wqs[rowB * 72 + c8A] = w1B;
        if (kt + 3 < 8) {
            int ko = (kt + 3) * 64;
            h1A = *(const uint4*)(HbB + (size_t)rowA * 512 + ko);
            h1B = *(const uint4*)(HbB + (size_t)rowB * 512 + ko);
            w1A = *(const uint4*)(WqB + (size_t)rowA * 512 + ko);
            w1B = *(const uint4*)(WqB + (size_t)rowB * 512 + ko);
        }
        __syncthreads();
        #pragma unroll
        for (int s = 0; s < 2; ++s) {
            int fk = s * 32 + fg * 8;
            bf16x8 hq = *(const bf16x8*)&Hs[(wid * 16 + fr) * 72 + fk];
            #pragma unroll
            for (int n = 0; n < 4; ++n) {
                bf16x8 wq = *(const bf16x8*)&Wqs[(n * 16 + fr) * 72 + fk];
                accQ[n] = __builtin_amdgcn_mfma_f32_16x16x32_bf16(hq, wq, accQ[n], 0, 0, 0);
            }
        }
        __syncthreads();
    }
    #pragma unroll
    for (int n = 0; n < 4; ++n) {
        int d = n * 16 + fr;
        float bq = bias[hoff + d];
        #pragma unroll
        for (int r = 0; r < 4; ++r) {
            int ql = wid * 16 + fg * 4 + r;
            Qs[ql * 72 + d] = f2b(accQ[n][r] + bq);
        }
    }
    __syncthreads();
    attn_phase<0>(Ks, Vt, Qs, Ps, qbase, brow, hoff, Op, lane, wid);
}

// ---------------------------------------------------------------------------
extern "C" void kernel_launch(void* const* d_in, const int* in_sizes, int n_in,
                              void* d_out, int out_size, void* d_ws, size_t ws_size,
                              hipStream_t stream)
{
    const int*   src       = (const int*)d_in[0];
    const int*   tgt       = (const int*)d_in[1];
    const float* src_emb   = (const float*)d_in[2];
    const float* tgt_emb   = (const float*)d_in[3];
    const float* enc_qkv_w = (const float*)d_in[4];
    const float* enc_qkv_b = (const float*)d_in[5];
    const float* enc_o_w   = (const float*)d_in[6];
    const float* enc_o_b   = (const float*)d_in[7];
    const float* enc_ff_w1 = (const float*)d_in[8];
    const float* enc_ff_b1 = (const float*)d_in[9];
    const float* enc_ff_w2 = (const float*)d_in[10];
    const float* enc_ff_b2 = (const float*)d_in[11];
    const float* enc_ln_g  = (const float*)d_in[12];
    const float* enc_ln_b  = (const float*)d_in[13];
    const float* enc_fg    = (const float*)d_in[14];
    const float* enc_fb    = (const float*)d_in[15];
    const float* dec_sqkv_w = (const float*)d_in[16];
    const float* dec_sqkv_b = (const float*)d_in[17];
    const float* dec_so_w   = (const float*)d_in[18];
    const float* dec_so_b   = (const float*)d_in[19];
    const float* dec_cqkv_w = (const float*)d_in[20];
    const float* dec_cqkv_b = (const float*)d_in[21];
    const float* dec_co_w   = (const float*)d_in[22];
    const float* dec_co_b   = (const float*)d_in[23];
    const float* dec_ff_w1  = (const float*)d_in[24];
    const float* dec_ff_b1  = (const float*)d_in[25];
    const float* dec_ff_w2  = (const float*)d_in[26];
    const float* dec_ff_b2  = (const float*)d_in[27];
    const float* dec_ln_g   = (const float*)d_in[28];
    const float* dec_ln_b   = (const float*)d_in[29];
    const float* dec_fg     = (const float*)d_in[30];
    const float* dec_fb     = (const float*)d_in[31];

    // ---- workspace carve ----
    unsigned short* wp = (unsigned short*)d_ws;
    unsigned short* WencQKV  = wp; wp += (size_t)6 * 786432;
    unsigned short* WencO    = wp; wp += (size_t)6 * 262144;
    unsigned short* WencF1   = wp; wp += (size_t)6 * 1048576;
    unsigned short* WencF2   = wp; wp += (size_t)6 * 1048576;
    unsigned short* WdecSQKV = wp; wp += (size_t)6 * 786432;
    unsigned short* WdecSO   = wp; wp += (size_t)6 * 262144;
    unsigned short* WdecCQKV = wp; wp += (size_t)6 * 786432;
    unsigned short* WdecCO   = wp; wp += (size_t)6 * 262144;
    unsigned short* WdecF1   = wp; wp += (size_t)6 * 1048576;
    unsigned short* WdecF2   = wp; wp += (size_t)6 * 1048576;
    unsigned short* Hb   = wp; wp += ROWS * D;
    unsigned short* QKVb = wp; wp += ROWS * 3 * D;
    unsigned short* CKVall = wp; wp += (size_t)6 * ROWS * 1024;
    unsigned short* ATTb = wp; wp += ROWS * D;
    unsigned short* F1b  = wp; wp += ROWS * DFF;
    unsigned short* MEMb = wp; wp += ROWS * D;
    float* X  = (float*)wp;  wp += ROWS * D * 2;   // fp32 encoder residual
    float* X2 = (float*)wp;  wp += ROWS * D * 2;   // fp32 decoder residual

    // ---- batched weight transposes: 3 launches (ALL 6 square groups) ----
    {
        TMulti mA = {{ {enc_qkv_w,  WencQKV,  18},
                       {enc_o_w,    WencO,     6},
                       {dec_sqkv_w, WdecSQKV, 18},
                       {dec_so_w,   WdecSO,    6},
                       {dec_cqkv_w, WdecCQKV, 18},
                       {dec_co_w,   WdecCO,    6} }};
        transpose_multi_kernel<<<dim3(16, 16, 72), 256, 0, stream>>>(mA, 512, 512);
        TMulti mB = {{ {enc_ff_w1, WencF1, 6},
                       {dec_ff_w1, WdecF1, 6},
                       {nullptr, nullptr, 1 << 30}, {nullptr, nullptr, 1 << 30},
                       {nullptr, nullptr, 1 << 30}, {nullptr, nullptr, 1 << 30} }};
        transpose_multi_kernel<<<dim3(64, 16, 12), 256, 0, stream>>>(mB, 512, 2048);
        TMulti mC = {{ {enc_ff_w2, WencF2, 6},
                       {dec_ff_w2, WdecF2, 6},
                       {nullptr, nullptr, 1 << 30}, {nullptr, nullptr, 1 << 30},
                       {nullptr, nullptr, 1 << 30}, {nullptr, nullptr, 1 << 30} }};
        transpose_multi_kernel<<<dim3(16, 64, 12), 256, 0, stream>>>(mC, 2048, 512);
    }

    // ---- both embeddings upfront (z=2) ----
    embed_pe_kernel<<<dim3(2048, 1, 2), 256, 0, stream>>>(src, tgt, src_emb, tgt_emb, X, X2);

    // ---------------- encoder ----------------
    for (int i = 0; i < LAYERS; ++i) {
        ln_kernel<1><<<256, 256, 0, stream>>>(X, enc_ln_g + (size_t)(i*2+0)*D, enc_ln_b + (size_t)(i*2+0)*D, Hb);
        mgemm_kernel<0,0,1><<<dim3(24,16,1), 256, 0, stream>>>(Hb, WencQKV + (size_t)i*786432,
                enc_qkv_b + (size_t)i*1536, nullptr, QKVb, 1536, 512, 0, 0, 0, 0);
        attn_kernel<0><<<128, 256, 0, stream>>>(QKVb, 1536, QKVb + 512, QKVb + 1024, 1536, ATTb);
        mgemm_kernel<1,0,0><<<dim3(8,16,1), 256, 0, stream>>>(ATTb, WencO + (size_t)i*262144,
                enc_o_b + (size_t)i*512, X, X, 512, 512, 0, 0, 0, 0);
        ln_kernel<1><<<256, 256, 0, stream>>>(X, enc_ln_g + (size_t)(i*2+1)*D, enc_ln_b + (size_t)(i*2+1)*D, Hb);
        mgemm_kernel<0,1,1><<<dim3(32,16,1), 256, 0, stream>>>(Hb, WencF1 + (size_t)i*1048576,
                enc_ff_b1 + (size_t)i*DFF, nullptr, F1b, DFF, 512, 0, 0, 0, 0);
        mgemm_kernel<1,0,0><<<dim3(8,16,1), 256, 0, stream>>>(F1b, WencF2 + (size_t)i*1048576,
                enc_ff_b2 + (size_t)i*512, X, X, 512, DFF, 0, 0, 0, 0);
    }
    ln_kernel<1><<<256, 256, 0, stream>>>(X, enc_fg, enc_fb, MEMb);

    // ---- all 6 decoder layers' cross K/V: one batched GEMM ----
    mgemm_kernel<0,0,1><<<dim3(16,16,6), 256, 0, stream>>>(MEMb, WdecCQKV + 262144,
            dec_cqkv_b + 512, nullptr, CKVall, 1024, 512,
            0, 786432, 1536, (long)ROWS * 1024);

    // ---------------- decoder ----------------
    for (int i = 0; i < LAYERS; ++i) {
        ln_kernel<1><<<256, 256, 0, stream>>>(X2, dec_ln_g + (size_t)(i*3+0)*D, dec_ln_b + (size_t)(i*3+0)*D, Hb);
        mgemm_kernel<0,0,1><<<dim3(24,16,1), 256, 0, stream>>>(Hb, WdecSQKV + (size_t)i*786432,
                dec_sqkv_b + (size_t)i*1536, nullptr, QKVb, 1536, 512, 0, 0, 0, 0);
        attn_kernel<1><<<128, 256, 0, stream>>>(QKVb, 1536, QKVb + 512, QKVb + 1024, 1536, ATTb);
        mgemm_kernel<1,0,0><<<dim3(8,16,1), 256, 0, stream>>>(ATTb, WdecSO + (size_t)i*262144,
                dec_so_b + (size_t)i*512, X2, X2, 512, 512, 0, 0, 0, 0);
        ln_kernel<1><<<256, 256, 0, stream>>>(X2, dec_ln_g + (size_t)(i*3+1)*D, dec_ln_b + (size_t)(i*3+1)*D, Hb);
        xattn_kernel<<<128, 256, 0, stream>>>(Hb, WdecCQKV + (size_t)i*786432,
                dec_cqkv_b + (size_t)i*1536, CKVall + (size_t)i*ROWS*1024, ATTb);
        mgemm_kernel<1,0,0><<<dim3(8,16,1), 256, 0, stream>>>(ATTb, WdecCO + (size_t)i*262144,
                dec_co_b + (size_t)i*512, X2, X2, 512, 512, 0, 0, 0, 0);
        ln_kernel<1><<<256, 256, 0, stream>>>(X2, dec_ln_g + (size_t)(i*3+2)*D, dec_ln_b + (size_t)(i*3+2)*D, Hb);
        mgemm_kernel<0,1,1><<<dim3(32,16,1), 256, 0, stream>>>(Hb, WdecF1 + (size_t)i*1048576,
                dec_ff_b1 + (size_t)i*DFF, nullptr, F1b, DFF, 512, 0, 0, 0, 0);
        mgemm_kernel<1,0,0><<<dim3(8,16,1), 256, 0, stream>>>(F1b, WdecF2 + (size_t)i*1048576,
                dec_ff_b2 + (size_t)i*512, X2, X2, 512, DFF, 0, 0, 0, 0);
    }
    ln_kernel<0><<<256, 256, 0, stream>>>(X2, dec_fg, dec_fb, d_out);
}

// Round 19
// 714.782 us; speedup vs baseline: 1.0622x; 1.0016x over previous
//
#include <hip/hip_runtime.h>
#include <hip/hip_bf16.h>
#include <math.h>

#define D 512
#define NH 8
#define DHEAD 64
#define LAYERS 6
#define DFF 2048
#define BATCH 8
#define SEQ 128
#define ROWS (BATCH * SEQ)   // 1024

typedef float f32x4 __attribute__((ext_vector_type(4)));
typedef short bf16x8 __attribute__((ext_vector_type(8)));

__device__ __forceinline__ unsigned short f2b(float x) {
    return __builtin_bit_cast(unsigned short, __float2bfloat16(x));
}

// ---------------- embedding + positional encoding (both streams, z=2) -------
__global__ __launch_bounds__(256) void embed_pe_kernel(
        const int* __restrict__ tok0, const int* __restrict__ tok1,
        const float* __restrict__ emb0, const float* __restrict__ emb1,
        float* __restrict__ out0, float* __restrict__ out1)
{
    const int z = blockIdx.z;
    const int* tok = z ? tok1 : tok0;
    const float* emb = z ? emb1 : emb0;
    float* out = z ? out1 : out0;
    int i = blockIdx.x * 256 + threadIdx.x;
    int bs = i >> 9;
    int d  = i & 511;
    int s  = bs & (SEQ - 1);
    int tk = tok[bs];
    float dv  = expf(-(float)(d & ~1) * (9.210340371976184f / 512.0f));
    float arg = (float)s * dv;
    float pe  = (d & 1) ? cosf(arg) : sinf(arg);
    out[i] = emb[(size_t)tk * D + d] * 22.627416997969522f + pe;
}

// ---------------- batched multi-source transpose + fp32->bf16 ---------------
struct TSeg { const float* src; unsigned short* dst; int cnt; };
struct TMulti { TSeg seg[6]; };

__global__ __launch_bounds__(256) void transpose_multi_kernel(TMulti m, int R, int C)
{
    __shared__ float t[32][33];
    int z = blockIdx.z, s = 0;
    while (z >= m.seg[s].cnt) { z -= m.seg[s].cnt; ++s; }
    const float* src = m.seg[s].src + (size_t)z * R * C;
    unsigned short* dst = m.seg[s].dst + (size_t)z * R * C;
    const int r0 = blockIdx.y << 5, c0 = blockIdx.x << 5;
    const int tid = threadIdx.x;
    const int rr = tid >> 3, cc = (tid & 7) << 2;
    float4 v = *(const float4*)(src + (size_t)(r0 + rr) * C + c0 + cc);
    t[rr][cc] = v.x; t[rr][cc + 1] = v.y; t[rr][cc + 2] = v.z; t[rr][cc + 3] = v.w;
    __syncthreads();
    const int oc = tid >> 3, or4 = (tid & 7) << 2;
    ushort4 o;
    o.x = f2b(t[or4 + 0][oc]);
    o.y = f2b(t[or4 + 1][oc]);
    o.z = f2b(t[or4 + 2][oc]);
    o.w = f2b(t[or4 + 3][oc]);
    *(ushort4*)(dst + (size_t)(c0 + oc) * R + r0 + or4) = o;
}

// ---------------- LayerNorm: one wave per row of 512 ------------------------
template<int OUT_BF16>
__global__ __launch_bounds__(256) void ln_kernel(const float* __restrict__ x,
        const float* __restrict__ g, const float* __restrict__ bta,
        void* __restrict__ outp)
{
    int lane = threadIdx.x & 63;
    int row  = (blockIdx.x << 2) + (threadIdx.x >> 6);
    const float* xr = x + (size_t)row * D;
    int c = lane * 8;
    float4 v0 = *(const float4*)(xr + c);
    float4 v1 = *(const float4*)(xr + c + 4);
    float s  = v0.x + v0.y + v0.z + v0.w + v1.x + v1.y + v1.z + v1.w;
    float sq = v0.x*v0.x + v0.y*v0.y + v0.z*v0.z + v0.w*v0.w
             + v1.x*v1.x + v1.y*v1.y + v1.z*v1.z + v1.w*v1.w;
    #pragma unroll
    for (int o = 32; o; o >>= 1) {
        s  += __shfl_xor(s, o);
        sq += __shfl_xor(sq, o);
    }
    float mean = s * (1.0f / D);
    float var  = sq * (1.0f / D) - mean * mean;
    float inv  = rsqrtf(var + 1e-6f);
    float4 g0 = *(const float4*)(g + c),   g1 = *(const float4*)(g + c + 4);
    float4 b0 = *(const float4*)(bta + c), b1 = *(const float4*)(bta + c + 4);
    float4 o0, o1;
    o0.x = g0.x * (v0.x - mean) * inv + b0.x;
    o0.y = g0.y * (v0.y - mean) * inv + b0.y;
    o0.z = g0.z * (v0.z - mean) * inv + b0.z;
    o0.w = g0.w * (v0.w - mean) * inv + b0.w;
    o1.x = g1.x * (v1.x - mean) * inv + b1.x;
    o1.y = g1.y * (v1.y - mean) * inv + b1.y;
    o1.z = g1.z * (v1.z - mean) * inv + b1.z;
    o1.w = g1.w * (v1.w - mean) * inv + b1.w;
    if (OUT_BF16) {
        unsigned short* orow = (unsigned short*)outp + (size_t)row * D + c;
        uint4 o;
        o.x = (unsigned int)f2b(o0.x) | ((unsigned int)f2b(o0.y) << 16);
        o.y = (unsigned int)f2b(o0.z) | ((unsigned int)f2b(o0.w) << 16);
        o.z = (unsigned int)f2b(o1.x) | ((unsigned int)f2b(o1.y) << 16);
        o.w = (unsigned int)f2b(o1.z) | ((unsigned int)f2b(o1.w) << 16);
        *(uint4*)orow = o;
    } else {
        float* orow = (float*)outp + (size_t)row * D + c;
        *(float4*)(orow)     = o0;
        *(float4*)(orow + 4) = o1;
    }
}

// ---------------- bf16 MFMA GEMM (dbuf, BK=64, depth-2 prefetch, z-batch) ---
template<int RESID, int RELU, int OUT_BF16>
__global__ __launch_bounds__(256) void mgemm_kernel(
        const unsigned short* __restrict__ A,
        const unsigned short* __restrict__ Wt,
        const float* __restrict__ bias,
        const float* __restrict__ Rp,
        void* __restrict__ Cout,
        int N, int K,
        long aZ, long wZ, long bZ, long cZ)
{
    __shared__ unsigned short As[2][64][72];
    __shared__ unsigned short Bs[2][64][72];
    const long z = blockIdx.z;
    const unsigned short* Ab = A  + z * aZ;
    const unsigned short* Wb = Wt + z * wZ;
    const float* biasb = bias + z * bZ;
    const int tid  = threadIdx.x;
    const int lane = tid & 63, wid = tid >> 6;
    const int wm = wid >> 1, wn = wid & 1;
    const int bm = blockIdx.y << 6, bn = blockIdx.x << 6;
    const int srow = tid >> 2, sk = (tid & 3) << 4;
    const unsigned short* Ag = Ab + (size_t)(bm + srow) * K + sk;
    const unsigned short* Bg = Wb + (size_t)(bn + srow) * K + sk;
    const int fr = lane & 15;
    const int fk = (lane >> 4) << 3;
    f32x4 acc[2][2];
    #pragma unroll
    for (int i = 0; i < 2; ++i)
        #pragma unroll
        for (int j = 0; j < 2; ++j)
            acc[i][j] = (f32x4){0.f, 0.f, 0.f, 0.f};

    const int T = K >> 6;   // always even (8 or 32), >= 2
    uint4 a0_0 = *(const uint4*)Ag,        a1_0 = *(const uint4*)(Ag + 8);
    uint4 b0_0 = *(const uint4*)Bg,        b1_0 = *(const uint4*)(Bg + 8);
    uint4 a0_1 = *(const uint4*)(Ag + 64), a1_1 = *(const uint4*)(Ag + 72);
    uint4 b0_1 = *(const uint4*)(Bg + 64), b1_1 = *(const uint4*)(Bg + 72);
    const unsigned short* AgN = Ag + 128;
    const unsigned short* BgN = Bg + 128;
    int loaded = 2;

    for (int t = 0; t < T; t += 2) {
        *(uint4*)&As[0][srow][sk]     = a0_0;
        *(uint4*)&As[0][srow][sk + 8] = a1_0;
        *(uint4*)&Bs[0][srow][sk]     = b0_0;
        *(uint4*)&Bs[0][srow][sk + 8] = b1_0;
        if (loaded < T) {
            a0_0 = *(const uint4*)AgN; a1_0 = *(const uint4*)(AgN + 8);
            b0_0 = *(const uint4*)BgN; b1_0 = *(const uint4*)(BgN + 8);
            AgN += 64; BgN += 64; ++loaded;
        }
        __syncthreads();
        #pragma unroll
        for (int s = 0; s < 2; ++s) {
            bf16x8 af0 = *(const bf16x8*)&As[0][wm * 32 + fr][s * 32 + fk];
            bf16x8 af1 = *(const bf16x8*)&As[0][wm * 32 + 16 + fr][s * 32 + fk];
            bf16x8 bf0 = *(const bf16x8*)&Bs[0][wn * 32 + fr][s * 32 + fk];
            bf16x8 bf1 = *(const bf16x8*)&Bs[0][wn * 32 + 16 + fr][s * 32 + fk];
            acc[0][0] = __builtin_amdgcn_mfma_f32_16x16x32_bf16(af0, bf0, acc[0][0], 0, 0, 0);
            acc[0][1] = __builtin_amdgcn_mfma_f32_16x16x32_bf16(af0, bf1, acc[0][1], 0, 0, 0);
            acc[1][0] = __builtin_amdgcn_mfma_f32_16x16x32_bf16(af1, bf0, acc[1][0], 0, 0, 0);
            acc[1][1] = __builtin_amdgcn_mfma_f32_16x16x32_bf16(af1, bf1, acc[1][1], 0, 0, 0);
        }
        *(uint4*)&As[1][srow][sk]     = a0_1;
        *(uint4*)&As[1][srow][sk + 8] = a1_1;
        *(uint4*)&Bs[1][srow][sk]     = b0_1;
        *(uint4*)&Bs[1][srow][sk + 8] = b1_1;
        if (loaded < T) {
            a0_1 = *(const uint4*)AgN; a1_1 = *(const uint4*)(AgN + 8);
            b0_1 = *(const uint4*)BgN; b1_1 = *(const uint4*)(BgN + 8);
            AgN += 64; BgN += 64; ++loaded;
        }
        __syncthreads();
        #pragma unroll
        for (int s = 0; s < 2; ++s) {
            bf16x8 af0 = *(const bf16x8*)&As[1][wm * 32 + fr][s * 32 + fk];
            bf16x8 af1 = *(const bf16x8*)&As[1][wm * 32 + 16 + fr][s * 32 + fk];
            bf16x8 bf0 = *(const bf16x8*)&Bs[1][wn * 32 + fr][s * 32 + fk];
            bf16x8 bf1 = *(const bf16x8*)&Bs[1][wn * 32 + 16 + fr][s * 32 + fk];
            acc[0][0] = __builtin_amdgcn_mfma_f32_16x16x32_bf16(af0, bf0, acc[0][0], 0, 0, 0);
            acc[0][1] = __builtin_amdgcn_mfma_f32_16x16x32_bf16(af0, bf1, acc[0][1], 0, 0, 0);
            acc[1][0] = __builtin_amdgcn_mfma_f32_16x16x32_bf16(af1, bf0, acc[1][0], 0, 0, 0);
            acc[1][1] = __builtin_amdgcn_mfma_f32_16x16x32_bf16(af1, bf1, acc[1][1], 0, 0, 0);
        }
    }
    const int cr   = (lane >> 4) << 2;
    const int ccol = lane & 15;
    #pragma unroll
    for (int i = 0; i < 2; ++i)
        #pragma unroll
        for (int j = 0; j < 2; ++j) {
            int col = bn + wn * 32 + j * 16 + ccol;
            float bsv = biasb[col];
            #pragma unroll
            for (int r = 0; r < 4; ++r) {
                int row = bm + wm * 32 + i * 16 + cr + r;
                float v = acc[i][j][r] + bsv;
                if (RESID) v += Rp[(size_t)row * N + col];
                if (RELU)  v = fmaxf(v, 0.f);
                if (OUT_BF16) ((unsigned short*)Cout + z * cZ)[(size_t)row * N + col] = f2b(v);
                else          ((float*)Cout)[(size_t)row * N + col] = v;
            }
        }
}

// ============ shared attention phase =========================================
template<int CAUSAL>
__device__ __forceinline__ void attn_phase(
        const unsigned short* Ks, const unsigned short* Vt,
        const unsigned short* Qs, unsigned short* Ps,
        int qbase, int brow, int hoff, unsigned short* __restrict__ Op,
        int lane, int wid)
{
    const int fr = lane & 15, fg = lane >> 4;
    f32x4 accs[8];
    #pragma unroll
    for (int kf = 0; kf < 8; ++kf) accs[kf] = (f32x4){0.f, 0.f, 0.f, 0.f};
    bf16x8 aq0 = *(const bf16x8*)&Qs[(wid * 16 + fr) * 72 + fg * 8];
    bf16x8 aq1 = *(const bf16x8*)&Qs[(wid * 16 + fr) * 72 + 32 + fg * 8];
    #pragma unroll
    for (int kf = 0; kf < 8; ++kf) {
        bf16x8 bk0 = *(const bf16x8*)&Ks[(kf * 16 + fr) * 72 + fg * 8];
        bf16x8 bk1 = *(const bf16x8*)&Ks[(kf * 16 + fr) * 72 + 32 + fg * 8];
        accs[kf] = __builtin_amdgcn_mfma_f32_16x16x32_bf16(aq0, bk0, accs[kf], 0, 0, 0);
        accs[kf] = __builtin_amdgcn_mfma_f32_16x16x32_bf16(aq1, bk1, accs[kf], 0, 0, 0);
    }
    const float SC = 0.125f * 1.44269504f;
    float linv[4];
    #pragma unroll
    for (int r = 0; r < 4; ++r) {
        int qrow = qbase + wid * 16 + fg * 4 + r;
        float sv[8];
        #pragma unroll
        for (int kf = 0; kf < 8; ++kf) {
            float s = accs[kf][r] * SC;
            if (CAUSAL) {
                int key = kf * 16 + fr;
                if (key > qrow) s = -1e30f;
            }
            sv[kf] = s;
        }
        float m = sv[0];
        #pragma unroll
        for (int kf = 1; kf < 8; ++kf) m = fmaxf(m, sv[kf]);
        #pragma unroll
        for (int o = 1; o < 16; o <<= 1) m = fmaxf(m, __shfl_xor(m, o));
        float l = 0.f;
        #pragma unroll
        for (int kf = 0; kf < 8; ++kf) {
            float p = exp2f(sv[kf] - m);
            l += p;
            Ps[(wid * 16 + fg * 4 + r) * 136 + kf * 16 + fr] = f2b(p);
        }
        #pragma unroll
        for (int o = 1; o < 16; o <<= 1) l += __shfl_xor(l, o);
        linv[r] = 1.f / l;
    }
    f32x4 acco[4];
    #pragma unroll
    for (int df = 0; df < 4; ++df) acco[df] = (f32x4){0.f, 0.f, 0.f, 0.f};
    #pragma unroll
    for (int ks = 0; ks < 4; ++ks) {
        bf16x8 pa = *(const bf16x8*)&Ps[(wid * 16 + fr) * 136 + ks * 32 + fg * 8];
        #pragma unroll
        for (int df = 0; df < 4; ++df) {
            bf16x8 vb = *(const bf16x8*)&Vt[(df * 16 + fr) * 136 + ks * 32 + fg * 8];
            acco[df] = __builtin_amdgcn_mfma_f32_16x16x32_bf16(pa, vb, acco[df], 0, 0, 0);
        }
    }
    #pragma unroll
    for (int df = 0; df < 4; ++df)
        #pragma unroll
        for (int r = 0; r < 4; ++r) {
            int qrow = qbase + wid * 16 + fg * 4 + r;
            Op[(size_t)(brow + qrow) * D + hoff + df * 16 + fr] = f2b(acco[df][r] * linv[r]);
        }
}

// ---------------- standalone attention (load-all-then-write staging) --------
template<int CAUSAL>
__global__ __launch_bounds__(256) void attn_kernel(
        const unsigned short* __restrict__ Qp, int qs,
        const unsigned short* __restrict__ Kp,
        const unsigned short* __restrict__ Vp, int kvs,
        unsigned short* __restrict__ Op)
{
    __shared__ unsigned short Ks[128 * 72];
    __shared__ unsigned short Qs[64 * 72];
    __shared__ unsigned short Vt[64 * 136];
    __shared__ unsigned short Ps[64 * 136];
    const int bh    = blockIdx.x >> 1;
    const int qbase = (blockIdx.x & 1) << 6;
    const int brow  = (bh >> 3) * SEQ;
    const int hoff  = (bh & 7) * DHEAD;
    const int tid = threadIdx.x, lane = tid & 63, wid = tid >> 6;

    // ---- issue ALL global loads into registers first (T14 split) ----
    uint4 kv[4], vv[4], qv[2];
    #pragma unroll
    for (int it = 0; it < 4; ++it) {
        int idx = it * 256 + tid;
        int row = idx >> 3;
        int c8  = (idx & 7) << 3;
        kv[it] = *(const uint4*)(Kp + (size_t)(brow + row) * kvs + hoff + c8);
        vv[it] = *(const uint4*)(Vp + (size_t)(brow + row) * kvs + hoff + c8);
    }
    #pragma unroll
    for (int it = 0; it < 2; ++it) {
        int idx = it * 256 + tid;
        int row = idx >> 3;
        int c8  = (idx & 7) << 3;
        qv[it] = *(const uint4*)(Qp + (size_t)(brow + qbase + row) * qs + hoff + c8);
    }
    // ---- drain to LDS ----
    #pragma unroll
    for (int it = 0; it < 4; ++it) {
        int idx = it * 256 + tid;
        int row = idx >> 3;
        int c8  = (idx & 7) << 3;
        *(uint4*)&Ks[row * 72 + c8] = kv[it];
        unsigned arr[4] = {vv[it].x, vv[it].y, vv[it].z, vv[it].w};
        #pragma unroll
        for (int j = 0; j < 8; ++j)
            Vt[(c8 + j) * 136 + row] = (unsigned short)(arr[j >> 1] >> ((j & 1) * 16));
    }
    #pragma unroll
    for (int it = 0; it < 2; ++it) {
        int idx = it * 256 + tid;
        int row = idx >> 3;
        int c8  = (idx & 7) << 3;
        *(uint4*)&Qs[row * 72 + c8] = qv[it];
    }
    __syncthreads();
    attn_phase<CAUSAL>(Ks, Vt, Qs, Ps, qbase, brow, hoff, Op, lane, wid);
}

// ---------------- fused Q-proj + cross-attention (depth-2 prefetch) ---------
__global__ __launch_bounds__(256) void xattn_kernel(
        const unsigned short* __restrict__ Hb,   // [1024][512] dec LN'd
        const unsigned short* __restrict__ Wq,   // [512][512] q^T (first block)
        const float* __restrict__ bias,          // [1536] (q at offset 0)
        const unsigned short* __restrict__ KV,   // [1024][1024]
        unsigned short* __restrict__ Op)
{
    __shared__ __align__(16) char lds[63488];
    unsigned short* Ks  = (unsigned short*)(lds);
    unsigned short* Vt  = (unsigned short*)(lds + 18432);
    unsigned short* Qs  = (unsigned short*)(lds + 35840);
    unsigned short* Ps  = (unsigned short*)(lds + 46080);
    unsigned short* Hs  = (unsigned short*)(lds + 35840);
    unsigned short* Wqs = (unsigned short*)(lds + 46080);

    const int bh = blockIdx.x >> 1;
    const int qbase = (blockIdx.x & 1) << 6;
    const int h = bh & 7;
    const int brow = (bh >> 3) * SEQ;
    const int hoff = h * DHEAD;
    const int tid = threadIdx.x, lane = tid & 63, wid = tid >> 6;
    const int fr = lane & 15, fg = lane >> 4;

    // ---- K/V staging: load-all-then-write ----
    uint4 kv[4], vv[4];
    #pragma unroll
    for (int it = 0; it < 4; ++it) {
        int idx = it * 256 + tid;
        int row = idx >> 3, c8 = (idx & 7) << 3;
        const unsigned short* kvrow = KV + (size_t)(brow + row) * 1024 + hoff;
        kv[it] = *(const uint4*)(kvrow + c8);
        vv[it] = *(const uint4*)(kvrow + 512 + c8);
    }
    #pragma unroll
    for (int it = 0; it < 4; ++it) {
        int idx = it * 256 + tid;
        int row = idx >> 3, c8 = (idx & 7) << 3;
        *(uint4*)&Ks[row * 72 + c8] = kv[it];
        unsigned arr[4] = {vv[it].x, vv[it].y, vv[it].z, vv[it].w};
        #pragma unroll
        for (int j = 0; j < 8; ++j)
            Vt[(c8 + j) * 136 + row] = (unsigned short)(arr[j >> 1] >> ((j & 1) * 16));
    }
    // ---- Q projection with depth-2 register prefetch ----
    const int rowA = tid >> 3, c8A = (tid & 7) << 3;
    const int rowB = rowA + 32;
    const unsigned short* HbB = Hb + (size_t)(brow + qbase) * 512 + c8A;
    const unsigned short* WqB = Wq + (size_t)hoff * 512 + c8A;
    f32x4 accQ[4];
    #pragma unroll
    for (int n = 0; n < 4; ++n) accQ[n] = (f32x4){0.f, 0.f, 0.f, 0.f};

    uint4 h0A = *(const uint4*)(HbB + (size_t)rowA * 512);
    uint4 h0B = *(const uint4*)(HbB + (size_t)rowB * 512);
    uint4 w0A = *(const uint4*)(WqB + (size_t)rowA * 512);
    uint4 w0B = *(const uint4*)(WqB + (size_t)rowB * 512);
    uint4 h1A = *(const uint4*)(HbB + (size_t)rowA * 512 + 64);
    uint4 h1B = *(const uint4*)(HbB + (size_t)rowB * 512 + 64);
    uint4 w1A = *(const uint4*)(WqB + (size_t)rowA * 512 + 64);
    uint4 w1B = *(const uint4*)(WqB + (size_t)rowB * 512 + 64);

    for (int kt = 0; kt < 8; kt += 2) {
        *(uint4*)&Hs[rowA * 72 + c8A]  = h0A;
        *(uint4*)&Hs[rowB * 72 + c8A]  = h0B;
        *(uint4*)&Wqs[rowA * 72 + c8A] = w0A;
        *(uint4*)&Wqs[rowB * 72 + c8A] = w0B;
        if (kt + 2 < 8) {
            int ko = (kt + 2) * 64;
            h0A = *(const uint4*)(HbB + (size_t)rowA * 512 + ko);
            h0B = *(const uint4*)(HbB + (size_t)rowB * 512 + ko);
            w0A = *(const uint4*)(WqB + (size_t)rowA * 512 + ko);
            w0B = *(const uint4*)(WqB + (size_t)rowB * 512 + ko);
        }
        __syncthreads();
        #pragma unroll
        for (int s = 0; s < 2; ++s) {
            int fk = s * 32 + fg * 8;
            bf16x8 hq = *(const bf16x8*)&Hs[(wid * 16 + fr) * 72 + fk];
            #pragma unroll
            for (int n = 0; n < 4; ++n) {
                bf16x8 wq = *(const bf16x8*)&Wqs[(n * 16 + fr) * 72 + fk];
                accQ[n] = __builtin_amdgcn_mfma_f32_16x16x32_bf16(hq, wq, accQ[n], 0, 0, 0);
            }
        }
        __syncthreads();
        *(uint4*)&Hs[rowA * 72 + c8A]  = h1A;
        *(uint4*)&Hs[rowB * 72 + c8A]  = h1B;
        *(uint4*)&Wqs[rowA * 72 + c8A] = w1A;
        *(uint4*)&Wqs[rowB * 72 + c8A] = w1B;
        if (kt + 3 < 8) {
            int ko = (kt + 3) * 64;
            h1A = *(const uint4*)(HbB + (size_t)rowA * 512 + ko);
            h1B = *(const uint4*)(HbB + (size_t)rowB * 512 + ko);
            w1A = *(const uint4*)(WqB + (size_t)rowA * 512 + ko);
            w1B = *(const uint4*)(WqB + (size_t)rowB * 512 + ko);
        }
        __syncthreads();
        #pragma unroll
        for (int s = 0; s < 2; ++s) {
            int fk = s * 32 + fg * 8;
            bf16x8 hq = *(const bf16x8*)&Hs[(wid * 16 + fr) * 72 + fk];
            #pragma unroll
            for (int n = 0; n < 4; ++n) {
                bf16x8 wq = *(const bf16x8*)&Wqs[(n * 16 + fr) * 72 + fk];
                accQ[n] = __builtin_amdgcn_mfma_f32_16x16x32_bf16(hq, wq, accQ[n], 0, 0, 0);
            }
        }
        __syncthreads();
    }
    #pragma unroll
    for (int n = 0; n < 4; ++n) {
        int d = n * 16 + fr;
        float bq = bias[hoff + d];
        #pragma unroll
        for (int r = 0; r < 4; ++r) {
            int ql = wid * 16 + fg * 4 + r;
            Qs[ql * 72 + d] = f2b(accQ[n][r] + bq);
        }
    }
    __syncthreads();
    attn_phase<0>(Ks, Vt, Qs, Ps, qbase, brow, hoff, Op, lane, wid);
}

// ---------------------------------------------------------------------------
extern "C" void kernel_launch(void* const* d_in, const int* in_sizes, int n_in,
                              void* d_out, int out_size, void* d_ws, size_t ws_size,
                              hipStream_t stream)
{
    const int*   src       = (const int*)d_in[0];
    const int*   tgt       = (const int*)d_in[1];
    const float* src_emb   = (const float*)d_in[2];
    const float* tgt_emb   = (const float*)d_in[3];
    const float* enc_qkv_w = (const float*)d_in[4];
    const float* enc_qkv_b = (const float*)d_in[5];
    const float* enc_o_w   = (const float*)d_in[6];
    const float* enc_o_b   = (const float*)d_in[7];
    const float* enc_ff_w1 = (const float*)d_in[8];
    const float* enc_ff_b1 = (const float*)d_in[9];
    const float* enc_ff_w2 = (const float*)d_in[10];
    const float* enc_ff_b2 = (const float*)d_in[11];
    const float* enc_ln_g  = (const float*)d_in[12];
    const float* enc_ln_b  = (const float*)d_in[13];
    const float* enc_fg    = (const float*)d_in[14];
    const float* enc_fb    = (const float*)d_in[15];
    const float* dec_sqkv_w = (const float*)d_in[16];
    const float* dec_sqkv_b = (const float*)d_in[17];
    const float* dec_so_w   = (const float*)d_in[18];
    const float* dec_so_b   = (const float*)d_in[19];
    const float* dec_cqkv_w = (const float*)d_in[20];
    const float* dec_cqkv_b = (const float*)d_in[21];
    const float* dec_co_w   = (const float*)d_in[22];
    const float* dec_co_b   = (const float*)d_in[23];
    const float* dec_ff_w1  = (const float*)d_in[24];
    const float* dec_ff_b1  = (const float*)d_in[25];
    const float* dec_ff_w2  = (const float*)d_in[26];
    const float* dec_ff_b2  = (const float*)d_in[27];
    const float* dec_ln_g   = (const float*)d_in[28];
    const float* dec_ln_b   = (const float*)d_in[29];
    const float* dec_fg     = (const float*)d_in[30];
    const float* dec_fb     = (const float*)d_in[31];

    // ---- workspace carve ----
    unsigned short* wp = (unsigned short*)d_ws;
    unsigned short* WencQKV  = wp; wp += (size_t)6 * 786432;
    unsigned short* WencO    = wp; wp += (size_t)6 * 262144;
    unsigned short* WencF1   = wp; wp += (size_t)6 * 1048576;
    unsigned short* WencF2   = wp; wp += (size_t)6 * 1048576;
    unsigned short* WdecSQKV = wp; wp += (size_t)6 * 786432;
    unsigned short* WdecSO   = wp; wp += (size_t)6 * 262144;
    unsigned short* WdecCQKV = wp; wp += (size_t)6 * 786432;
    unsigned short* WdecCO   = wp; wp += (size_t)6 * 262144;
    unsigned short* WdecF1   = wp; wp += (size_t)6 * 1048576;
    unsigned short* WdecF2   = wp; wp += (size_t)6 * 1048576;
    unsigned short* Hb   = wp; wp += ROWS * D;
    unsigned short* QKVb = wp; wp += ROWS * 3 * D;
    unsigned short* CKVall = wp; wp += (size_t)6 * ROWS * 1024;
    unsigned short* ATTb = wp; wp += ROWS * D;
    unsigned short* F1b  = wp; wp += ROWS * DFF;
    unsigned short* MEMb = wp; wp += ROWS * D;
    float* X  = (float*)wp;  wp += ROWS * D * 2;   // fp32 encoder residual
    float* X2 = (float*)wp;  wp += ROWS * D * 2;   // fp32 decoder residual

    // ---- batched weight transposes: 3 launches (ALL 6 square groups) ----
    {
        TMulti mA = {{ {enc_qkv_w,  WencQKV,  18},
                       {enc_o_w,    WencO,     6},
                       {dec_sqkv_w, WdecSQKV, 18},
                       {dec_so_w,   WdecSO,    6},
                       {dec_cqkv_w, WdecCQKV, 18},
                       {dec_co_w,   WdecCO,    6} }};
        transpose_multi_kernel<<<dim3(16, 16, 72), 256, 0, stream>>>(mA, 512, 512);
        TMulti mB = {{ {enc_ff_w1, WencF1, 6},
                       {dec_ff_w1, WdecF1, 6},
                       {nullptr, nullptr, 1 << 30}, {nullptr, nullptr, 1 << 30},
                       {nullptr, nullptr, 1 << 30}, {nullptr, nullptr, 1 << 30} }};
        transpose_multi_kernel<<<dim3(64, 16, 12), 256, 0, stream>>>(mB, 512, 2048);
        TMulti mC = {{ {enc_ff_w2, WencF2, 6},
                       {dec_ff_w2, WdecF2, 6},
                       {nullptr, nullptr, 1 << 30}, {nullptr, nullptr, 1 << 30},
                       {nullptr, nullptr, 1 << 30}, {nullptr, nullptr, 1 << 30} }};
        transpose_multi_kernel<<<dim3(16, 64, 12), 256, 0, stream>>>(mC, 2048, 512);
    }

    // ---- both embeddings upfront (z=2) ----
    embed_pe_kernel<<<dim3(2048, 1, 2), 256, 0, stream>>>(src, tgt, src_emb, tgt_emb, X, X2);

    // ---------------- encoder ----------------
    for (int i = 0; i < LAYERS; ++i) {
        ln_kernel<1><<<256, 256, 0, stream>>>(X, enc_ln_g + (size_t)(i*2+0)*D, enc_ln_b + (size_t)(i*2+0)*D, Hb);
        mgemm_kernel<0,0,1><<<dim3(24,16,1), 256, 0, stream>>>(Hb, WencQKV + (size_t)i*786432,
                enc_qkv_b + (size_t)i*1536, nullptr, QKVb, 1536, 512, 0, 0, 0, 0);
        attn_kernel<0><<<128, 256, 0, stream>>>(QKVb, 1536, QKVb + 512, QKVb + 1024, 1536, ATTb);
        mgemm_kernel<1,0,0><<<dim3(8,16,1), 256, 0, stream>>>(ATTb, WencO + (size_t)i*262144,
                enc_o_b + (size_t)i*512, X, X, 512, 512, 0, 0, 0, 0);
        ln_kernel<1><<<256, 256, 0, stream>>>(X, enc_ln_g + (size_t)(i*2+1)*D, enc_ln_b + (size_t)(i*2+1)*D, Hb);
        mgemm_kernel<0,1,1><<<dim3(32,16,1), 256, 0, stream>>>(Hb, WencF1 + (size_t)i*1048576,
                enc_ff_b1 + (size_t)i*DFF, nullptr, F1b, DFF, 512, 0, 0, 0, 0);
        mgemm_kernel<1,0,0><<<dim3(8,16,1), 256, 0, stream>>>(F1b, WencF2 + (size_t)i*1048576,
                enc_ff_b2 + (size_t)i*512, X, X, 512, DFF, 0, 0, 0, 0);
    }
    ln_kernel<1><<<256, 256, 0, stream>>>(X, enc_fg, enc_fb, MEMb);

    // ---- all 6 decoder layers' cross K/V: one batched GEMM ----
    mgemm_kernel<0,0,1><<<dim3(16,16,6), 256, 0, stream>>>(MEMb, WdecCQKV + 262144,
            dec_cqkv_b + 512, nullptr, CKVall, 1024, 512,
            0, 786432, 1536, (long)ROWS * 1024);

    // ---------------- decoder ----------------
    for (int i = 0; i < LAYERS; ++i) {
        ln_kernel<1><<<256, 256, 0, stream>>>(X2, dec_ln_g + (size_t)(i*3+0)*D, dec_ln_b + (size_t)(i*3+0)*D, Hb);
        mgemm_kernel<0,0,1><<<dim3(24,16,1), 256, 0, stream>>>(Hb, WdecSQKV + (size_t)i*786432,
                dec_sqkv_b + (size_t)i*1536, nullptr, QKVb, 1536, 512, 0, 0, 0, 0);
        attn_kernel<1><<<128, 256, 0, stream>>>(QKVb, 1536, QKVb + 512, QKVb + 1024, 1536, ATTb);
        mgemm_kernel<1,0,0><<<dim3(8,16,1), 256, 0, stream>>>(ATTb, WdecSO + (size_t)i*262144,
                dec_so_b + (size_t)i*512, X2, X2, 512, 512, 0, 0, 0, 0);
        ln_kernel<1><<<256, 256, 0, stream>>>(X2, dec_ln_g + (size_t)(i*3+1)*D, dec_ln_b + (size_t)(i*3+1)*D, Hb);
        xattn_kernel<<<128, 256, 0, stream>>>(Hb, WdecCQKV + (size_t)i*786432,
                dec_cqkv_b + (size_t)i*1536, CKVall + (size_t)i*ROWS*1024, ATTb);
        mgemm_kernel<1,0,0><<<dim3(8,16,1), 256, 0, stream>>>(ATTb, WdecCO + (size_t)i*262144,
                dec_co_b + (size_t)i*512, X2, X2, 512, 512, 0, 0, 0, 0);
        ln_kernel<1><<<256, 256, 0, stream>>>(X2, dec_ln_g + (size_t)(i*3+2)*D, dec_ln_b + (size_t)(i*3+2)*D, Hb);
        mgemm_kernel<0,1,1><<<dim3(32,16,1), 256, 0, stream>>>(Hb, WdecF1 + (size_t)i*1048576,
                dec_ff_b1 + (size_t)i*DFF, nullptr, F1b, DFF, 512, 0, 0, 0, 0);
        mgemm_kernel<1,0,0><<<dim3(8,16,1), 256, 0, stream>>>(F1b, WdecF2 + (size_t)i*1048576,
                dec_ff_b2 + (size_t)i*512, X2, X2, 512, DFF, 0, 0, 0, 0);
    }
    ln_kernel<0><<<256, 256, 0, stream>>>(X2, dec_fg, dec_fb, d_out);
}